// Round 11
// baseline (122.328 us; speedup 1.0000x reference)
//
#include <hip/hip_runtime.h>

#define DIMM 1024
#define NHEADS 16
#define HDIM 64
#define WIN 1024
#define GATEIN 20
#define BB 2
#define TT 2048
#define MTOT (BB*TT)   // 4096

typedef __attribute__((ext_vector_type(8))) short short8;
typedef __attribute__((ext_vector_type(4))) float f32x4;
typedef __attribute__((ext_vector_type(16))) float f32x16;
typedef const __attribute__((address_space(1))) void gvoid_t;
typedef __attribute__((address_space(3))) void lvoid_t;

__device__ __forceinline__ unsigned short f2b(float f) {
  union { float f; unsigned u; } c; c.f = f;
  unsigned u = c.u + 0x7fffu + ((c.u >> 16) & 1u);
  return (unsigned short)(u >> 16);
}
__device__ __forceinline__ float b2f(unsigned short s) {
  union { unsigned u; float f; } c; c.u = ((unsigned)s) << 16;
  return c.f;
}
__device__ __forceinline__ unsigned cvt_pk_bf16(float lo, float hi) {
  unsigned r;
  asm("v_cvt_pk_bf16_f32 %0, %1, %2" : "=v"(r) : "v"(lo), "v"(hi));
  return r;
}
__device__ __forceinline__ float max3f(float a, float b, float c) {
  return fmaxf(fmaxf(a, b), c);   // clang fuses to v_max3_f32
}
// cross-half (lane ^ 32) max via permlane32_swap (VALU, no DS)
__device__ __forceinline__ float xmax32(float x) {
  union { float f; unsigned u; } c; c.f = x;
  auto pr = __builtin_amdgcn_permlane32_swap(c.u, c.u, false, false);
  union { unsigned u; float f; } a, b; a.u = pr[0]; b.u = pr[1];
  return fmaxf(a.f, b.f);
}

// ---------------- fused prep: bf16-cast x, Wq|Wk|Wv, Wo; concat biases ----------------
__global__ void prep_kernel(const float* __restrict__ x,  const float* __restrict__ Wq,
                            const float* __restrict__ Wk, const float* __restrict__ Wv,
                            const float* __restrict__ Wo, const float* __restrict__ bq,
                            const float* __restrict__ bk, const float* __restrict__ bv,
                            unsigned short* __restrict__ xb, unsigned short* __restrict__ wqkv,
                            unsigned short* __restrict__ wob, float* __restrict__ bcat) {
  int i = blockIdx.x * blockDim.x + threadIdx.x;
  const float* src; unsigned short* dst; int off;
  if (i < 1048576)      { src = x;  dst = xb;             off = i; }
  else if (i < 1310720) { src = Wq; dst = wqkv;           off = i - 1048576; }
  else if (i < 1572864) { src = Wk; dst = wqkv + 1048576; off = i - 1310720; }
  else if (i < 1835008) { src = Wv; dst = wqkv + 2097152; off = i - 1572864; }
  else if (i < 2097152) { src = Wo; dst = wob;            off = i - 1835008; }
  else {
    int j = i - 2097152;            // 0..767 : bias f32 copy
    if (j < 768) {
      const float* bsrc = (j < 256) ? bq : (j < 512) ? bk : bv;
      int bo = (j & 255) * 4;
      int db = (j < 256) ? 0 : (j < 512) ? 1024 : 2048;
      *(float4*)(bcat + db + bo) = *(const float4*)(bsrc + bo);
    }
    return;
  }
  float4 v = ((const float4*)src)[off];
  union { unsigned short s[4]; uint2 u; } o;
  o.s[0] = f2b(v.x); o.s[1] = f2b(v.y); o.s[2] = f2b(v.z); o.s[3] = f2b(v.w);
  *(uint2*)(dst + (size_t)off * 4) = o.u;
}

// ---------------- gate = sigmoid(x[:, :20] @ Wg^T + bg), [M][H] f32 ----------------
__global__ void gate_kernel(const float* __restrict__ x, const float* __restrict__ Wg,
                            const float* __restrict__ bg, float* __restrict__ gate) {
  int i = blockIdx.x * blockDim.x + threadIdx.x;   // M*H
  if (i >= MTOT * NHEADS) return;
  int h = i & 15;
  int m = i >> 4;
  const float* xr = x + (size_t)m * DIMM;
  const float* wr = Wg + h * GATEIN;
  float z = bg[h];
#pragma unroll
  for (int g = 0; g < GATEIN; ++g) z += xr[g] * wr[g];
  gate[i] = 1.f / (1.f + __expf(-z));
}

// ---------------- GEMM: C[M,N] = A[M,K] @ Bw[N,K]^T + bias ----------------
// Tile = (MF*32) x 128, 4 waves. LDS XOR-swizzle (T2) + double-buffered 2-phase.
template<int MF, int OUTBF>
__global__ __launch_bounds__(256) void gemm_bt(const unsigned short* __restrict__ A,
                                               const unsigned short* __restrict__ Bw,
                                               const float* __restrict__ bias,
                                               void* __restrict__ Cout,
                                               int M, int N, int K) {
  __shared__ __align__(16) unsigned short As[2][MF * 32 * 32];
  __shared__ __align__(16) unsigned short Bs[2][128 * 32];
  const int tid = threadIdx.x;
  const int lane = tid & 63, wid = tid >> 6;
  const int g = lane >> 4, r16 = lane & 15;
  const int m0 = blockIdx.y * (MF * 32), n0 = blockIdx.x * 128;
  const int wr = (wid >> 1) * (MF * 16), wc = (wid & 1) * 64;
  const int wbase = wid * 64;

  int oaf[MF], obf[4];
#pragma unroll
  for (int mf = 0; mf < MF; ++mf) {
    int row = wr + mf * 16 + r16;
    oaf[mf] = row * 32 + ((g ^ ((row >> 1) & 3)) * 8);
  }
#pragma unroll
  for (int nf = 0; nf < 4; ++nf) {
    int row = wc + nf * 16 + r16;
    obf[nf] = row * 32 + ((g ^ ((row >> 1) & 3)) * 8);
  }

  f32x4 acc[MF][4];
#pragma unroll
  for (int i = 0; i < MF; ++i)
#pragma unroll
    for (int j = 0; j < 4; ++j) acc[i][j] = (f32x4){0.f, 0.f, 0.f, 0.f};

  auto stage = [&](int buf, int k0) {
#pragma unroll
    for (int j = 0; j < MF / 2; ++j) {
      int sbase = j * 256 + wbase;
      int s = sbase + lane;
      int l = s ^ ((s >> 3) & 3);
      const unsigned short* gA = A + (size_t)(m0 + (l >> 2)) * K + k0 + (l & 3) * 8;
      __builtin_amdgcn_global_load_lds((gvoid_t*)gA,
          (lvoid_t*)((char*)&As[buf][0] + sbase * 16), 16, 0, 0);
    }
#pragma unroll
    for (int j = 0; j < 2; ++j) {
      int sbase = j * 256 + wbase;
      int s = sbase + lane;
      int l = s ^ ((s >> 3) & 3);
      const unsigned short* gB = Bw + (size_t)(n0 + (l >> 2)) * K + k0 + (l & 3) * 8;
      __builtin_amdgcn_global_load_lds((gvoid_t*)gB,
          (lvoid_t*)((char*)&Bs[buf][0] + sbase * 16), 16, 0, 0);
    }
  };

  const int NT = K >> 5;
  stage(0, 0);
  __syncthreads();
  for (int t = 0; t < NT; ++t) {
    const int buf = t & 1;
    if (t + 1 < NT) stage(buf ^ 1, (t + 1) << 5);   // prefetch next tile
    short8 af[MF], bf[4];
#pragma unroll
    for (int mf = 0; mf < MF; ++mf) af[mf] = *(const short8*)(&As[buf][0] + oaf[mf]);
#pragma unroll
    for (int nf = 0; nf < 4; ++nf)  bf[nf] = *(const short8*)(&Bs[buf][0] + obf[nf]);
#pragma unroll
    for (int mf = 0; mf < MF; ++mf)
#pragma unroll
      for (int nf = 0; nf < 4; ++nf)
        acc[mf][nf] = __builtin_amdgcn_mfma_f32_16x16x32_bf16(af[mf], bf[nf], acc[mf][nf], 0, 0, 0);
    __syncthreads();   // drains prefetch (post-compute) + guards buf reuse
  }
#pragma unroll
  for (int mf = 0; mf < MF; ++mf)
#pragma unroll
    for (int nf = 0; nf < 4; ++nf)
#pragma unroll
      for (int rr = 0; rr < 4; ++rr) {
        int m = m0 + wr + mf * 16 + g * 4 + rr;
        int n = n0 + wc + nf * 16 + r16;
        float v = acc[mf][nf][rr] + bias[n];
        if (OUTBF) ((unsigned short*)Cout)[(size_t)m * N + n] = f2b(v);
        else       ((float*)Cout)[(size_t)m * N + n] = v;
      }
}

// ---------------- fused RoPE (q,k) + V transpose ----------------
#define QSCALE (0.125f * 1.4426950408889634f)
__global__ __launch_bounds__(256) void ropev_kernel(const unsigned short* __restrict__ qkv,
                                                    const float* __restrict__ cosb,
                                                    const float* __restrict__ sinb,
                                                    unsigned short* __restrict__ qr,
                                                    unsigned short* __restrict__ kr,
                                                    unsigned short* __restrict__ vt) {
  __shared__ unsigned short tile[64][66];
  const int t0 = blockIdx.x * 64;
  const int bh = blockIdx.y;
  const int b = bh >> 4, h = bh & 15;
  const int tid = threadIdx.x;
  const int tr = tid >> 2;          // 0..63 (row within tile)
  const int qd = tid & 3;           // quarter
  const int t = t0 + tr;
  const size_t base = (size_t)bh * TT * HDIM;
  const unsigned short* row = qkv + (size_t)(b * TT + t) * 3072 + h * 64;

  {
    const unsigned short* vsrc = row + 2048 + qd * 16;
    short8 v0 = *(const short8*)vsrc;
    short8 v1 = *(const short8*)(vsrc + 8);
#pragma unroll
    for (int j = 0; j < 8; ++j) {
      tile[tr][qd * 16 + j]     = (unsigned short)v0[j];
      tile[tr][qd * 16 + 8 + j] = (unsigned short)v1[j];
    }
  }

  {
    const int d0 = qd * 8;
    short8 q1 = *(const short8*)(row + d0);
    short8 q2 = *(const short8*)(row + d0 + 32);
    short8 k1 = *(const short8*)(row + 1024 + d0);
    short8 k2 = *(const short8*)(row + 1024 + d0 + 32);
    float4 c0 = *(const float4*)(cosb + t * 32 + d0);
    float4 c1 = *(const float4*)(cosb + t * 32 + d0 + 4);
    float4 s0 = *(const float4*)(sinb + t * 32 + d0);
    float4 s1 = *(const float4*)(sinb + t * 32 + d0 + 4);
    float cc[8] = {c0.x, c0.y, c0.z, c0.w, c1.x, c1.y, c1.z, c1.w};
    float ss[8] = {s0.x, s0.y, s0.z, s0.w, s1.x, s1.y, s1.z, s1.w};
    short8 qo1, qo2, ko1, ko2;
#pragma unroll
    for (int j = 0; j < 8; ++j) {
      float a1 = b2f((unsigned short)q1[j]), a2 = b2f((unsigned short)q2[j]);
      float b1 = b2f((unsigned short)k1[j]), b2v = b2f((unsigned short)k2[j]);
      qo1[j] = (short)f2b((a1 * cc[j] - a2 * ss[j]) * QSCALE);
      qo2[j] = (short)f2b((a1 * ss[j] + a2 * cc[j]) * QSCALE);
      ko1[j] = (short)f2b(b1 * cc[j] - b2v * ss[j]);
      ko2[j] = (short)f2b(b1 * ss[j] + b2v * cc[j]);
    }
    *(short8*)(qr + base + (size_t)t * HDIM + d0)      = qo1;
    *(short8*)(qr + base + (size_t)t * HDIM + d0 + 32) = qo2;
    size_t ok = base + (size_t)(t >> 5) * 2048 + (size_t)(qd >> 1) * 512
              + (size_t)(qd & 1) * 256 + (size_t)(t & 31) * 8;
    *(short8*)(kr + ok)        = ko1;
    *(short8*)(kr + ok + 1024) = ko2;   // d+32 -> st+2
  }
  __syncthreads();

  {
    const int d = tid >> 2;           // 0..63
    const int tc = (tid & 3) * 16;    // key chunk of 16
    short8 o0, o1;
#pragma unroll
    for (int j = 0; j < 8; ++j) {
      o0[j] = (short)tile[tc + j][d];
      o1[j] = (short)tile[tc + 8 + j][d];
    }
    int kt = (t0 + tc) >> 5;
    int n  = (tc >> 4) & 1;
    int m  = d >> 5, l31v = d & 31;
    size_t A0 = base + (size_t)kt * 2048 + (size_t)(m * 2 + n) * 512 + (size_t)l31v * 8;
    *(short8*)(vt + A0)       = o0;
    *(short8*)(vt + A0 + 256) = o1;
  }
}

// ---------------- flash attention: 4-way split-KV, KVBLK=64, swapped QK^T ----------------
// Two independent S chains per step (ILP-2), one softmax round per 64 keys.
// Range padded to x64 by extending kv_start down (window mask absorbs) or by a
// phantom upper half (causal mask absorbs; always in-bounds since q0<=1024 there).
// Register budget deliberately sits in the 129-256 unified-reg bracket (same
// occupancy as R9's 144) — the doubling is occupancy-free.
__global__ __launch_bounds__(256) void attn_kernel(const unsigned short* __restrict__ qr,
                                                   const unsigned short* __restrict__ kr,
                                                   const unsigned short* __restrict__ vt,
                                                   const float* __restrict__ gate,
                                                   unsigned short* __restrict__ attn_out) {
  __shared__ float lds_m[4][32];
  __shared__ float lds_l[4][32];
  __shared__ float lds_O[3][64][33];
  const int tid = threadIdx.x;
  const int lane = tid & 63, wid = tid >> 6;
  const int l31 = lane & 31, hi = lane >> 5;

  const int fid = blockIdx.x;
  const int idx = fid >> 3;                 // 0..255
  const int bh = (fid & 7) * 4 + (idx & 3);
  const int qt = 63 - (idx >> 2);
  const int q0 = qt * 32;
  const int b = bh >> 4, h = bh & 15;
  const unsigned short* kptr = kr + (size_t)bh * TT * HDIM;
  const unsigned short* vptr = vt + (size_t)bh * TT * HDIM;
  const int q = q0 + l31;

  short8 qf[4];
#pragma unroll
  for (int st = 0; st < 4; ++st)
    qf[st] = *(const short8*)(qr + (size_t)bh * TT * HDIM + (size_t)q * HDIM + st * 16 + hi * 8);

  f32x16 SZERO;
#pragma unroll
  for (int r = 0; r < 16; ++r) SZERO[r] = 0.f;
  short8 ONES;
#pragma unroll
  for (int j = 0; j < 8; ++j) ONES[j] = (short)0x3F80;   // bf16 1.0

  f32x16 o0 = SZERO, o1 = SZERO;
  float mrun = -1e30f, lrun = 0.f;

  int kv_start = (q0 >= WIN) ? (q0 - WIN) : 0;
  const int kv_hi = q0 + 32;
  if (((kv_hi - kv_start) & 63) && kv_start >= 32) kv_start -= 32;

  for (int kv = kv_start + wid * 64; kv < kv_hi; kv += 256) {
    const bool causal = (kv + 64 > q0);            // step contains/overruns the diagonal
    const bool window = (q0 >= WIN) && (kv == kv_start);

    // 16 coalesced fragment loads (2 K-tiles + 2 V-tiles)
    const unsigned short* kfA = kptr + (size_t)kv * 64 + lane * 8;
    short8 kA0 = *(const short8*)(kfA);
    short8 kA1 = *(const short8*)(kfA + 512);
    short8 kA2 = *(const short8*)(kfA + 1024);
    short8 kA3 = *(const short8*)(kfA + 1536);
    short8 kB0 = *(const short8*)(kfA + 2048);
    short8 kB1 = *(const short8*)(kfA + 2560);
    short8 kB2 = *(const short8*)(kfA + 3072);
    short8 kB3 = *(const short8*)(kfA + 3584);
    const unsigned short* vfA = vptr + (size_t)kv * 64 + lane * 8;
    short8 vA00 = *(const short8*)(vfA);
    short8 vA01 = *(const short8*)(vfA + 512);
    short8 vA10 = *(const short8*)(vfA + 1024);
    short8 vA11 = *(const short8*)(vfA + 1536);
    short8 vB00 = *(const short8*)(vfA + 2048);
    short8 vB01 = *(const short8*)(vfA + 2560);
    short8 vB10 = *(const short8*)(vfA + 3072);
    short8 vB11 = *(const short8*)(vfA + 3584);

    // two independent S chains
    f32x16 s0, s1;
    s0 = __builtin_amdgcn_mfma_f32_32x32x16_bf16(kA0, qf[0], SZERO, 0, 0, 0);
    s1 = __builtin_amdgcn_mfma_f32_32x32x16_bf16(kB0, qf[0], SZERO, 0, 0, 0);
    s0 = __builtin_amdgcn_mfma_f32_32x32x16_bf16(kA1, qf[1], s0, 0, 0, 0);
    s1 = __builtin_amdgcn_mfma_f32_32x32x16_bf16(kB1, qf[1], s1, 0, 0, 0);
    s0 = __builtin_amdgcn_mfma_f32_32x32x16_bf16(kA2, qf[2], s0, 0, 0, 0);
    s1 = __builtin_amdgcn_mfma_f32_32x32x16_bf16(kB2, qf[2], s1, 0, 0, 0);
    s0 = __builtin_amdgcn_mfma_f32_32x32x16_bf16(kA3, qf[3], s0, 0, 0, 0);
    s1 = __builtin_amdgcn_mfma_f32_32x32x16_bf16(kB3, qf[3], s1, 0, 0, 0);

    // masks (wave-uniform branches; only peeled steps pay)
    if (causal) {
#pragma unroll
      for (int r = 0; r < 16; ++r) {
        int keyr = (r & 3) + 8 * (r >> 2) + 4 * hi;
        s0[r] = (kv + keyr <= q)      ? s0[r] : -1e30f;
        s1[r] = (kv + 32 + keyr <= q) ? s1[r] : -1e30f;
      }
    }
    if (window) {
#pragma unroll
      for (int r = 0; r < 16; ++r) {
        int keyr = (r & 3) + 8 * (r >> 2) + 4 * hi;
        s0[r] = (kv + keyr + WIN >= q)      ? s0[r] : -1e30f;
        s1[r] = (kv + 32 + keyr + WIN >= q) ? s1[r] : -1e30f;
      }
    }

    // row-max over 64 keys: two max3 trees + combine + cross-half swap
    float u0 = max3f(s0[0],  s0[1],  s0[2]);
    float u1 = max3f(s0[3],  s0[4],  s0[5]);
    float u2 = max3f(s0[6],  s0[7],  s0[8]);
    float u3 = max3f(s0[9],  s0[10], s0[11]);
    float u4 = max3f(s0[12], s0[13], s0[14]);
    float lmA = fmaxf(max3f(u0, u1, u2), max3f(u3, u4, s0[15]));
    float w0m = max3f(s1[0],  s1[1],  s1[2]);
    float w1m = max3f(s1[3],  s1[4],  s1[5]);
    float w2m = max3f(s1[6],  s1[7],  s1[8]);
    float w3m = max3f(s1[9],  s1[10], s1[11]);
    float w4m = max3f(s1[12], s1[13], s1[14]);
    float lmB = fmaxf(max3f(w0m, w1m, w2m), max3f(w3m, w4m, s1[15]));
    float lm = xmax32(fmaxf(lmA, lmB));

    if (!__all(lm - mrun <= 8.f)) {
      float mnew = fmaxf(mrun, lm);
      float scf = __builtin_exp2f(mrun - mnew);
      mrun = mnew;
      lrun *= scf;
#pragma unroll
      for (int r = 0; r < 16; ++r) { o0[r] *= scf; o1[r] *= scf; }
    }

    // P = exp2(s - mrun) in place; masked entries underflow to 0
#pragma unroll
    for (int r = 0; r < 16; ++r) s0[r] = __builtin_exp2f(s0[r] - mrun);
#pragma unroll
    for (int r = 0; r < 16; ++r) s1[r] = __builtin_exp2f(s1[r] - mrun);

    // P -> bf16 fragments: cvt_pk + permlane32_swap (T12), x2
    unsigned a0 = cvt_pk_bf16(s0[0],  s0[1]),  a1 = cvt_pk_bf16(s0[2],  s0[3]);
    unsigned a2 = cvt_pk_bf16(s0[4],  s0[5]),  a3 = cvt_pk_bf16(s0[6],  s0[7]);
    unsigned a4 = cvt_pk_bf16(s0[8],  s0[9]),  a5 = cvt_pk_bf16(s0[10], s0[11]);
    unsigned a6 = cvt_pk_bf16(s0[12], s0[13]), a7 = cvt_pk_bf16(s0[14], s0[15]);
    unsigned b0u = cvt_pk_bf16(s1[0],  s1[1]),  b1u = cvt_pk_bf16(s1[2],  s1[3]);
    unsigned b2u = cvt_pk_bf16(s1[4],  s1[5]),  b3u = cvt_pk_bf16(s1[6],  s1[7]);
    unsigned b4u = cvt_pk_bf16(s1[8],  s1[9]),  b5u = cvt_pk_bf16(s1[10], s1[11]);
    unsigned b6u = cvt_pk_bf16(s1[12], s1[13]), b7u = cvt_pk_bf16(s1[14], s1[15]);
    auto p1 = __builtin_amdgcn_permlane32_swap(a0, a2, false, false);
    auto p2 = __builtin_amdgcn_permlane32_swap(a1, a3, false, false);
    auto p3 = __builtin_amdgcn_permlane32_swap(a4, a6, false, false);
    auto p4 = __builtin_amdgcn_permlane32_swap(a5, a7, false, false);
    auto p5 = __builtin_amdgcn_permlane32_swap(b0u, b2u, false, false);
    auto p6 = __builtin_amdgcn_permlane32_swap(b1u, b3u, false, false);
    auto p7 = __builtin_amdgcn_permlane32_swap(b4u, b6u, false, false);
    auto p8 = __builtin_amdgcn_permlane32_swap(b5u, b7u, false, false);
    union { unsigned u[4]; short8 s8; } pf0, pf1, pf2, pf3;
    pf0.u[0] = p1[0]; pf0.u[1] = p2[0]; pf0.u[2] = p1[1]; pf0.u[3] = p2[1];
    pf1.u[0] = p3[0]; pf1.u[1] = p4[0]; pf1.u[2] = p3[1]; pf1.u[3] = p4[1];
    pf2.u[0] = p5[0]; pf2.u[1] = p6[0]; pf2.u[2] = p5[1]; pf2.u[3] = p6[1];
    pf3.u[0] = p7[0]; pf3.u[1] = p8[0]; pf3.u[2] = p7[1]; pf3.u[3] = p8[1];

    // row-sum via ones-fragment MFMA (4 accumulating)
    f32x16 ls;
    ls = __builtin_amdgcn_mfma_f32_32x32x16_bf16(ONES, pf0.s8, SZERO, 0, 0, 0);
    ls = __builtin_amdgcn_mfma_f32_32x32x16_bf16(ONES, pf1.s8, ls, 0, 0, 0);
    ls = __builtin_amdgcn_mfma_f32_32x32x16_bf16(ONES, pf2.s8, ls, 0, 0, 0);
    ls = __builtin_amdgcn_mfma_f32_32x32x16_bf16(ONES, pf3.s8, ls, 0, 0, 0);

    // O^T += V^T @ P^T (8 MFMA, 2 acc chains)
    o0 = __builtin_amdgcn_mfma_f32_32x32x16_bf16(vA00, pf0.s8, o0, 0, 0, 0);
    o1 = __builtin_amdgcn_mfma_f32_32x32x16_bf16(vA10, pf0.s8, o1, 0, 0, 0);
    o0 = __builtin_amdgcn_mfma_f32_32x32x16_bf16(vA01, pf1.s8, o0, 0, 0, 0);
    o1 = __builtin_amdgcn_mfma_f32_32x32x16_bf16(vA11, pf1.s8, o1, 0, 0, 0);
    o0 = __builtin_amdgcn_mfma_f32_32x32x16_bf16(vB00, pf2.s8, o0, 0, 0, 0);
    o1 = __builtin_amdgcn_mfma_f32_32x32x16_bf16(vB10, pf2.s8, o1, 0, 0, 0);
    o0 = __builtin_amdgcn_mfma_f32_32x32x16_bf16(vB01, pf3.s8, o0, 0, 0, 0);
    o1 = __builtin_amdgcn_mfma_f32_32x32x16_bf16(vB11, pf3.s8, o1, 0, 0, 0);

    lrun += ls[0];
  }

  // ---- combine across the 4 waves ----
  if (hi == 0) { lds_m[wid][l31] = mrun; lds_l[wid][l31] = lrun; }
  __syncthreads();
  float m0 = lds_m[0][l31], m1 = lds_m[1][l31], m2 = lds_m[2][l31], m3 = lds_m[3][l31];
  float mstar = fmaxf(fmaxf(m0, m1), fmaxf(m2, m3));
  float myscale = __builtin_exp2f(mrun - mstar);
  if (wid != 0) {
#pragma unroll
    for (int r = 0; r < 16; ++r) {
      lds_O[wid - 1][lane][r]      = o0[r] * myscale;
      lds_O[wid - 1][lane][16 + r] = o1[r] * myscale;
    }
  }
  __syncthreads();
  if (wid == 0) {
    float lstar = __builtin_exp2f(m0 - mstar) * lds_l[0][l31]
                + __builtin_exp2f(m1 - mstar) * lds_l[1][l31]
                + __builtin_exp2f(m2 - mstar) * lds_l[2][l31]
                + __builtin_exp2f(m3 - mstar) * lds_l[3][l31];
    float gv = gate[((size_t)b * TT + q) * NHEADS + h];
    float inv = gv / lstar;
    float of0[16], of1[16];
#pragma unroll
    for (int r = 0; r < 16; ++r) {
      of0[r] = o0[r] * myscale + lds_O[0][lane][r]      + lds_O[1][lane][r]      + lds_O[2][lane][r];
      of1[r] = o1[r] * myscale + lds_O[0][lane][16 + r] + lds_O[1][lane][16 + r] + lds_O[2][lane][16 + r];
    }
    unsigned short* orow = attn_out + ((size_t)b * TT + q) * DIMM + h * HDIM;
#pragma unroll
    for (int a2 = 0; a2 < 4; ++a2) {
      int d0 = a2 * 8 + hi * 4;
      union { unsigned short s[4]; uint2 u; } x0, x1;
#pragma unroll
      for (int c = 0; c < 4; ++c) {
        x0.s[c] = f2b(of0[a2 * 4 + c] * inv);
        x1.s[c] = f2b(of1[a2 * 4 + c] * inv);
      }
      *(uint2*)(orow + d0) = x0.u;
      *(uint2*)(orow + 32 + d0) = x1.u;
    }
  }
}

// ---------------- workspace layout (bytes) ----------------
#define OFF_XB    ((size_t)0)
#define OFF_WQKV  ((size_t)8388608)
#define OFF_WO    ((size_t)14680064)
#define OFF_BCAT  ((size_t)16777216)
#define OFF_QKV   ((size_t)16793600)
#define OFF_QR    ((size_t)41959424)
#define OFF_KR    ((size_t)50348032)
#define OFF_VT    ((size_t)58736640)
#define OFF_ATTN  ((size_t)67125248)
#define OFF_GATE  ((size_t)75513856)

extern "C" void kernel_launch(void* const* d_in, const int* in_sizes, int n_in,
                              void* d_out, int out_size, void* d_ws, size_t ws_size,
                              hipStream_t stream) {
  const float* x    = (const float*)d_in[0];
  const float* Wq   = (const float*)d_in[1];
  const float* bq   = (const float*)d_in[2];
  const float* Wk   = (const float*)d_in[3];
  const float* bk   = (const float*)d_in[4];
  const float* Wv   = (const float*)d_in[5];
  const float* bv   = (const float*)d_in[6];
  const float* Wo   = (const float*)d_in[7];
  const float* bo   = (const float*)d_in[8];
  const float* Wg   = (const float*)d_in[9];
  const float* bg   = (const float*)d_in[10];
  const float* cosb = (const float*)d_in[11];
  const float* sinb = (const float*)d_in[12];
  float* out = (float*)d_out;
  char* ws = (char*)d_ws;

  unsigned short* xb    = (unsigned short*)(ws + OFF_XB);
  unsigned short* wqkv  = (unsigned short*)(ws + OFF_WQKV);
  unsigned short* wob   = (unsigned short*)(ws + OFF_WO);
  float*          bcat  = (float*)(ws + OFF_BCAT);
  unsigned short* qkv   = (unsigned short*)(ws + OFF_QKV);
  unsigned short* q_r   = (unsigned short*)(ws + OFF_QR);
  unsigned short* k_r   = (unsigned short*)(ws + OFF_KR);
  unsigned short* v_t   = (unsigned short*)(ws + OFF_VT);
  unsigned short* attn  = (unsigned short*)(ws + OFF_ATTN);
  float*          gateb = (float*)(ws + OFF_GATE);

  prep_kernel<<<8195, 256, 0, stream>>>(x, Wq, Wk, Wv, Wo, bq, bk, bv, xb, wqkv, wob, bcat);
  gate_kernel<<<256, 256, 0, stream>>>(x, Wg, bg, gateb);

  // fused QKV projection: [4096,1024] @ [3072,1024]^T (dbuf 2-phase, swizzled LDS)
  gemm_bt<4, 1><<<dim3(24, 32), 256, 0, stream>>>(xb, wqkv, bcat, qkv, MTOT, 3072, 1024);

  // fused RoPE + V transpose
  ropev_kernel<<<dim3(32, 32), 256, 0, stream>>>(qkv, cosb, sinb, q_r, k_r, v_t);

  // windowed causal flash attention + gate (KVBLK=64)
  attn_kernel<<<2048, 256, 0, stream>>>(q_r, k_r, v_t, gateb, attn);

  // output projection: [4096,1024] @ [1024,1024]^T + bo (dbuf 2-phase)
  gemm_bt<2, 0><<<dim3(8, 64), 256, 0, stream>>>(attn, wob, bo, out, MTOT, 1024, 1024);
}

// Round 12
// 107.673 us; speedup vs baseline: 1.1361x; 1.1361x over previous
//
#include <hip/hip_runtime.h>

#define DIMM 1024
#define NHEADS 16
#define HDIM 64
#define WIN 1024
#define GATEIN 20
#define BB 2
#define TT 2048
#define MTOT (BB*TT)   // 4096

typedef __attribute__((ext_vector_type(8))) short short8;
typedef __attribute__((ext_vector_type(4))) float f32x4;
typedef __attribute__((ext_vector_type(16))) float f32x16;
typedef const __attribute__((address_space(1))) void gvoid_t;
typedef __attribute__((address_space(3))) void lvoid_t;

__device__ __forceinline__ unsigned short f2b(float f) {
  union { float f; unsigned u; } c; c.f = f;
  unsigned u = c.u + 0x7fffu + ((c.u >> 16) & 1u);
  return (unsigned short)(u >> 16);
}
__device__ __forceinline__ float b2f(unsigned short s) {
  union { unsigned u; float f; } c; c.u = ((unsigned)s) << 16;
  return c.f;
}
__device__ __forceinline__ unsigned cvt_pk_bf16(float lo, float hi) {
  unsigned r;
  asm("v_cvt_pk_bf16_f32 %0, %1, %2" : "=v"(r) : "v"(lo), "v"(hi));
  return r;
}
__device__ __forceinline__ float max3f(float a, float b, float c) {
  return fmaxf(fmaxf(a, b), c);   // clang fuses to v_max3_f32
}
// cross-half (lane ^ 32) reductions via permlane32_swap (VALU, no DS)
__device__ __forceinline__ float xmax32(float x) {
  union { float f; unsigned u; } c; c.f = x;
  auto pr = __builtin_amdgcn_permlane32_swap(c.u, c.u, false, false);
  union { unsigned u; float f; } a, b; a.u = pr[0]; b.u = pr[1];
  return fmaxf(a.f, b.f);
}
__device__ __forceinline__ float xsum32(float x) {
  union { float f; unsigned u; } c; c.f = x;
  auto pr = __builtin_amdgcn_permlane32_swap(c.u, c.u, false, false);
  union { unsigned u; float f; } a, b; a.u = pr[0]; b.u = pr[1];
  return a.f + b.f;
}

// ---------------- fused prep: bf16-cast x, Wq|Wk|Wv, Wo; concat biases ----------------
__global__ void prep_kernel(const float* __restrict__ x,  const float* __restrict__ Wq,
                            const float* __restrict__ Wk, const float* __restrict__ Wv,
                            const float* __restrict__ Wo, const float* __restrict__ bq,
                            const float* __restrict__ bk, const float* __restrict__ bv,
                            unsigned short* __restrict__ xb, unsigned short* __restrict__ wqkv,
                            unsigned short* __restrict__ wob, float* __restrict__ bcat) {
  int i = blockIdx.x * blockDim.x + threadIdx.x;
  const float* src; unsigned short* dst; int off;
  if (i < 1048576)      { src = x;  dst = xb;             off = i; }
  else if (i < 1310720) { src = Wq; dst = wqkv;           off = i - 1048576; }
  else if (i < 1572864) { src = Wk; dst = wqkv + 1048576; off = i - 1310720; }
  else if (i < 1835008) { src = Wv; dst = wqkv + 2097152; off = i - 1572864; }
  else if (i < 2097152) { src = Wo; dst = wob;            off = i - 1835008; }
  else {
    int j = i - 2097152;            // 0..767 : bias f32 copy
    if (j < 768) {
      const float* bsrc = (j < 256) ? bq : (j < 512) ? bk : bv;
      int bo = (j & 255) * 4;
      int db = (j < 256) ? 0 : (j < 512) ? 1024 : 2048;
      *(float4*)(bcat + db + bo) = *(const float4*)(bsrc + bo);
    }
    return;
  }
  float4 v = ((const float4*)src)[off];
  union { unsigned short s[4]; uint2 u; } o;
  o.s[0] = f2b(v.x); o.s[1] = f2b(v.y); o.s[2] = f2b(v.z); o.s[3] = f2b(v.w);
  *(uint2*)(dst + (size_t)off * 4) = o.u;
}

// ---------------- gate = sigmoid(x[:, :20] @ Wg^T + bg), [M][H] f32 ----------------
__global__ void gate_kernel(const float* __restrict__ x, const float* __restrict__ Wg,
                            const float* __restrict__ bg, float* __restrict__ gate) {
  int i = blockIdx.x * blockDim.x + threadIdx.x;   // M*H
  if (i >= MTOT * NHEADS) return;
  int h = i & 15;
  int m = i >> 4;
  const float* xr = x + (size_t)m * DIMM;
  const float* wr = Wg + h * GATEIN;
  float z = bg[h];
#pragma unroll
  for (int g = 0; g < GATEIN; ++g) z += xr[g] * wr[g];
  gate[i] = 1.f / (1.f + __expf(-z));
}

// ---------------- GEMM: C[M,N] = A[M,K] @ Bw[N,K]^T + bias ----------------
// Tile = (MF*32) x 128, 4 waves. LDS XOR-swizzle (T2) + double-buffered 2-phase.
template<int MF, int OUTBF>
__global__ __launch_bounds__(256) void gemm_bt(const unsigned short* __restrict__ A,
                                               const unsigned short* __restrict__ Bw,
                                               const float* __restrict__ bias,
                                               void* __restrict__ Cout,
                                               int M, int N, int K) {
  __shared__ __align__(16) unsigned short As[2][MF * 32 * 32];
  __shared__ __align__(16) unsigned short Bs[2][128 * 32];
  const int tid = threadIdx.x;
  const int lane = tid & 63, wid = tid >> 6;
  const int g = lane >> 4, r16 = lane & 15;
  const int m0 = blockIdx.y * (MF * 32), n0 = blockIdx.x * 128;
  const int wr = (wid >> 1) * (MF * 16), wc = (wid & 1) * 64;
  const int wbase = wid * 64;

  int oaf[MF], obf[4];
#pragma unroll
  for (int mf = 0; mf < MF; ++mf) {
    int row = wr + mf * 16 + r16;
    oaf[mf] = row * 32 + ((g ^ ((row >> 1) & 3)) * 8);
  }
#pragma unroll
  for (int nf = 0; nf < 4; ++nf) {
    int row = wc + nf * 16 + r16;
    obf[nf] = row * 32 + ((g ^ ((row >> 1) & 3)) * 8);
  }

  f32x4 acc[MF][4];
#pragma unroll
  for (int i = 0; i < MF; ++i)
#pragma unroll
    for (int j = 0; j < 4; ++j) acc[i][j] = (f32x4){0.f, 0.f, 0.f, 0.f};

  auto stage = [&](int buf, int k0) {
#pragma unroll
    for (int j = 0; j < MF / 2; ++j) {
      int sbase = j * 256 + wbase;
      int s = sbase + lane;
      int l = s ^ ((s >> 3) & 3);
      const unsigned short* gA = A + (size_t)(m0 + (l >> 2)) * K + k0 + (l & 3) * 8;
      __builtin_amdgcn_global_load_lds((gvoid_t*)gA,
          (lvoid_t*)((char*)&As[buf][0] + sbase * 16), 16, 0, 0);
    }
#pragma unroll
    for (int j = 0; j < 2; ++j) {
      int sbase = j * 256 + wbase;
      int s = sbase + lane;
      int l = s ^ ((s >> 3) & 3);
      const unsigned short* gB = Bw + (size_t)(n0 + (l >> 2)) * K + k0 + (l & 3) * 8;
      __builtin_amdgcn_global_load_lds((gvoid_t*)gB,
          (lvoid_t*)((char*)&Bs[buf][0] + sbase * 16), 16, 0, 0);
    }
  };

  const int NT = K >> 5;
  stage(0, 0);
  __syncthreads();
  for (int t = 0; t < NT; ++t) {
    const int buf = t & 1;
    if (t + 1 < NT) stage(buf ^ 1, (t + 1) << 5);   // prefetch next tile
    short8 af[MF], bf[4];
#pragma unroll
    for (int mf = 0; mf < MF; ++mf) af[mf] = *(const short8*)(&As[buf][0] + oaf[mf]);
#pragma unroll
    for (int nf = 0; nf < 4; ++nf)  bf[nf] = *(const short8*)(&Bs[buf][0] + obf[nf]);
#pragma unroll
    for (int mf = 0; mf < MF; ++mf)
#pragma unroll
      for (int nf = 0; nf < 4; ++nf)
        acc[mf][nf] = __builtin_amdgcn_mfma_f32_16x16x32_bf16(af[mf], bf[nf], acc[mf][nf], 0, 0, 0);
    __syncthreads();   // drains prefetch (post-compute) + guards buf reuse
  }
#pragma unroll
  for (int mf = 0; mf < MF; ++mf)
#pragma unroll
    for (int nf = 0; nf < 4; ++nf)
#pragma unroll
      for (int rr = 0; rr < 4; ++rr) {
        int m = m0 + wr + mf * 16 + g * 4 + rr;
        int n = n0 + wc + nf * 16 + r16;
        float v = acc[mf][nf][rr] + bias[n];
        if (OUTBF) ((unsigned short*)Cout)[(size_t)m * N + n] = f2b(v);
        else       ((float*)Cout)[(size_t)m * N + n] = v;
      }
}

// ---------------- fused RoPE (q,k) + V transpose ----------------
#define QSCALE (0.125f * 1.4426950408889634f)
__global__ __launch_bounds__(256) void ropev_kernel(const unsigned short* __restrict__ qkv,
                                                    const float* __restrict__ cosb,
                                                    const float* __restrict__ sinb,
                                                    unsigned short* __restrict__ qr,
                                                    unsigned short* __restrict__ kr,
                                                    unsigned short* __restrict__ vt) {
  __shared__ unsigned short tile[64][66];
  const int t0 = blockIdx.x * 64;
  const int bh = blockIdx.y;
  const int b = bh >> 4, h = bh & 15;
  const int tid = threadIdx.x;
  const int tr = tid >> 2;          // 0..63 (row within tile)
  const int qd = tid & 3;           // quarter
  const int t = t0 + tr;
  const size_t base = (size_t)bh * TT * HDIM;
  const unsigned short* row = qkv + (size_t)(b * TT + t) * 3072 + h * 64;

  {
    const unsigned short* vsrc = row + 2048 + qd * 16;
    short8 v0 = *(const short8*)vsrc;
    short8 v1 = *(const short8*)(vsrc + 8);
#pragma unroll
    for (int j = 0; j < 8; ++j) {
      tile[tr][qd * 16 + j]     = (unsigned short)v0[j];
      tile[tr][qd * 16 + 8 + j] = (unsigned short)v1[j];
    }
  }

  {
    const int d0 = qd * 8;
    short8 q1 = *(const short8*)(row + d0);
    short8 q2 = *(const short8*)(row + d0 + 32);
    short8 k1 = *(const short8*)(row + 1024 + d0);
    short8 k2 = *(const short8*)(row + 1024 + d0 + 32);
    float4 c0 = *(const float4*)(cosb + t * 32 + d0);
    float4 c1 = *(const float4*)(cosb + t * 32 + d0 + 4);
    float4 s0 = *(const float4*)(sinb + t * 32 + d0);
    float4 s1 = *(const float4*)(sinb + t * 32 + d0 + 4);
    float cc[8] = {c0.x, c0.y, c0.z, c0.w, c1.x, c1.y, c1.z, c1.w};
    float ss[8] = {s0.x, s0.y, s0.z, s0.w, s1.x, s1.y, s1.z, s1.w};
    short8 qo1, qo2, ko1, ko2;
#pragma unroll
    for (int j = 0; j < 8; ++j) {
      float a1 = b2f((unsigned short)q1[j]), a2 = b2f((unsigned short)q2[j]);
      float b1 = b2f((unsigned short)k1[j]), b2v = b2f((unsigned short)k2[j]);
      qo1[j] = (short)f2b((a1 * cc[j] - a2 * ss[j]) * QSCALE);
      qo2[j] = (short)f2b((a1 * ss[j] + a2 * cc[j]) * QSCALE);
      ko1[j] = (short)f2b(b1 * cc[j] - b2v * ss[j]);
      ko2[j] = (short)f2b(b1 * ss[j] + b2v * cc[j]);
    }
    *(short8*)(qr + base + (size_t)t * HDIM + d0)      = qo1;
    *(short8*)(qr + base + (size_t)t * HDIM + d0 + 32) = qo2;
    size_t ok = base + (size_t)(t >> 5) * 2048 + (size_t)(qd >> 1) * 512
              + (size_t)(qd & 1) * 256 + (size_t)(t & 31) * 8;
    *(short8*)(kr + ok)        = ko1;
    *(short8*)(kr + ok + 1024) = ko2;   // d+32 -> st+2
  }
  __syncthreads();

  {
    const int d = tid >> 2;           // 0..63
    const int tc = (tid & 3) * 16;    // key chunk of 16
    short8 o0, o1;
#pragma unroll
    for (int j = 0; j < 8; ++j) {
      o0[j] = (short)tile[tc + j][d];
      o1[j] = (short)tile[tc + 8 + j][d];
    }
    int kt = (t0 + tc) >> 5;
    int n  = (tc >> 4) & 1;
    int m  = d >> 5, l31v = d & 31;
    size_t A0 = base + (size_t)kt * 2048 + (size_t)(m * 2 + n) * 512 + (size_t)l31v * 8;
    *(short8*)(vt + A0)       = o0;
    *(short8*)(vt + A0 + 256) = o1;
  }
}

// ---------------- flash attention: 4-way split-KV, KVBLK=32, swapped QK^T ----------------
// R11: register-dieted R9 structure targeting <=128 unified regs -> 4 waves/SIMD
// (m69 bracket). Cuts vs R9: no ones-MFMA row-sum (VALU tree instead, -36 regs),
// V loads moved after softmax (-16 peak-live). __launch_bounds__(256,4) enforces.
__global__ __launch_bounds__(256, 4) void attn_kernel(const unsigned short* __restrict__ qr,
                                                      const unsigned short* __restrict__ kr,
                                                      const unsigned short* __restrict__ vt,
                                                      const float* __restrict__ gate,
                                                      unsigned short* __restrict__ attn_out) {
  __shared__ float lds_m[4][32];
  __shared__ float lds_l[4][32];
  __shared__ float lds_O[3][64][33];
  const int tid = threadIdx.x;
  const int lane = tid & 63, wid = tid >> 6;
  const int l31 = lane & 31, hi = lane >> 5;

  const int fid = blockIdx.x;
  const int idx = fid >> 3;                 // 0..255
  const int bh = (fid & 7) * 4 + (idx & 3);
  const int qt = 63 - (idx >> 2);
  const int q0 = qt * 32;
  const int b = bh >> 4, h = bh & 15;
  const unsigned short* kptr = kr + (size_t)bh * TT * HDIM;
  const unsigned short* vptr = vt + (size_t)bh * TT * HDIM;
  const int q = q0 + l31;

  short8 qf[4];
#pragma unroll
  for (int st = 0; st < 4; ++st)
    qf[st] = *(const short8*)(qr + (size_t)bh * TT * HDIM + (size_t)q * HDIM + st * 16 + hi * 8);

  f32x16 o0, o1;
#pragma unroll
  for (int r = 0; r < 16; ++r) { o0[r] = 0.f; o1[r] = 0.f; }
  float mrun = -1e30f, lrun = 0.f;

  int kv_lo = q0 - WIN;
  if (kv_lo < 0) kv_lo = 0;
  const int kv_hi = q0 + 32;

  for (int kv = kv_lo + wid * 32; kv < kv_hi; kv += 128) {
    const unsigned short* kf = kptr + (size_t)kv * 64 + lane * 8;
    short8 k0 = *(const short8*)(kf);
    short8 k1 = *(const short8*)(kf + 512);
    short8 k2 = *(const short8*)(kf + 1024);
    short8 k3 = *(const short8*)(kf + 1536);

    f32x16 s;
#pragma unroll
    for (int r = 0; r < 16; ++r) s[r] = 0.f;
    s = __builtin_amdgcn_mfma_f32_32x32x16_bf16(k0, qf[0], s, 0, 0, 0);
    s = __builtin_amdgcn_mfma_f32_32x32x16_bf16(k1, qf[1], s, 0, 0, 0);
    s = __builtin_amdgcn_mfma_f32_32x32x16_bf16(k2, qf[2], s, 0, 0, 0);
    s = __builtin_amdgcn_mfma_f32_32x32x16_bf16(k3, qf[3], s, 0, 0, 0);

    // masks only on peeled steps (wave-uniform branches), in place
    if (kv == q0) {
#pragma unroll
      for (int r = 0; r < 16; ++r) {
        int key = kv + (r & 3) + 8 * (r >> 2) + 4 * hi;
        s[r] = (key <= q) ? s[r] : -1e30f;
      }
    } else if (q0 >= WIN && kv == kv_lo) {
#pragma unroll
      for (int r = 0; r < 16; ++r) {
        int key = kv + (r & 3) + 8 * (r >> 2) + 4 * hi;
        s[r] = (key + WIN >= q) ? s[r] : -1e30f;
      }
    }

    // row-max: max3 tree (depth 3) + cross-half swap
    float t0 = max3f(s[0],  s[1],  s[2]);
    float t1 = max3f(s[3],  s[4],  s[5]);
    float t2 = max3f(s[6],  s[7],  s[8]);
    float t3 = max3f(s[9],  s[10], s[11]);
    float t4 = max3f(s[12], s[13], s[14]);
    float lm = fmaxf(max3f(t0, t1, t2), max3f(t3, t4, s[15]));
    lm = xmax32(lm);

    if (!__all(lm - mrun <= 8.f)) {
      float mnew = fmaxf(mrun, lm);
      float scf = __builtin_exp2f(mrun - mnew);
      mrun = mnew;
      lrun *= scf;
#pragma unroll
      for (int r = 0; r < 16; ++r) { o0[r] *= scf; o1[r] *= scf; }
    }

    // P = exp2(s - mrun) in place; masked entries underflow to 0
#pragma unroll
    for (int r = 0; r < 16; ++r) s[r] = __builtin_exp2f(s[r] - mrun);

    // row-sum: pair-add tree + cross-half swap (replaces R9's ones-MFMA; -36 regs)
    float c0 = (s[0] + s[1]) + (s[2] + s[3]);
    float c1 = (s[4] + s[5]) + (s[6] + s[7]);
    float c2 = (s[8] + s[9]) + (s[10] + s[11]);
    float c3 = (s[12] + s[13]) + (s[14] + s[15]);
    lrun += xsum32((c0 + c1) + (c2 + c3));

    // P -> bf16 B-frags: cvt_pk + permlane32_swap (T12)
    unsigned w0 = cvt_pk_bf16(s[0],  s[1]),  w1 = cvt_pk_bf16(s[2],  s[3]);
    unsigned w2 = cvt_pk_bf16(s[4],  s[5]),  w3 = cvt_pk_bf16(s[6],  s[7]);
    unsigned w4 = cvt_pk_bf16(s[8],  s[9]),  w5 = cvt_pk_bf16(s[10], s[11]);
    unsigned w6 = cvt_pk_bf16(s[12], s[13]), w7 = cvt_pk_bf16(s[14], s[15]);
    auto s1p = __builtin_amdgcn_permlane32_swap(w0, w2, false, false);
    auto s2p = __builtin_amdgcn_permlane32_swap(w1, w3, false, false);
    auto s3p = __builtin_amdgcn_permlane32_swap(w4, w6, false, false);
    auto s4p = __builtin_amdgcn_permlane32_swap(w5, w7, false, false);
    union { unsigned u[4]; short8 s8; } pf0, pf1;
    pf0.u[0] = s1p[0]; pf0.u[1] = s2p[0]; pf0.u[2] = s1p[1]; pf0.u[3] = s2p[1];
    pf1.u[0] = s3p[0]; pf1.u[1] = s4p[0]; pf1.u[2] = s3p[1]; pf1.u[3] = s4p[1];

    // V loads after softmax (peak-live reduction; TLP at 4 waves/SIMD hides latency)
    const unsigned short* vf = vptr + (size_t)kv * 64 + lane * 8;
    short8 vf00 = *(const short8*)(vf);
    short8 vf01 = *(const short8*)(vf + 512);
    short8 vf10 = *(const short8*)(vf + 1024);
    short8 vf11 = *(const short8*)(vf + 1536);

    o0 = __builtin_amdgcn_mfma_f32_32x32x16_bf16(vf00, pf0.s8, o0, 0, 0, 0);
    o1 = __builtin_amdgcn_mfma_f32_32x32x16_bf16(vf10, pf0.s8, o1, 0, 0, 0);
    o0 = __builtin_amdgcn_mfma_f32_32x32x16_bf16(vf01, pf1.s8, o0, 0, 0, 0);
    o1 = __builtin_amdgcn_mfma_f32_32x32x16_bf16(vf11, pf1.s8, o1, 0, 0, 0);
  }

  // ---- combine across the 4 waves ----
  if (hi == 0) { lds_m[wid][l31] = mrun; lds_l[wid][l31] = lrun; }
  __syncthreads();
  float m0 = lds_m[0][l31], m1 = lds_m[1][l31], m2 = lds_m[2][l31], m3 = lds_m[3][l31];
  float mstar = fmaxf(fmaxf(m0, m1), fmaxf(m2, m3));
  float myscale = __builtin_exp2f(mrun - mstar);
  if (wid != 0) {
#pragma unroll
    for (int r = 0; r < 16; ++r) {
      lds_O[wid - 1][lane][r]      = o0[r] * myscale;
      lds_O[wid - 1][lane][16 + r] = o1[r] * myscale;
    }
  }
  __syncthreads();
  if (wid == 0) {
    float lstar = __builtin_exp2f(m0 - mstar) * lds_l[0][l31]
                + __builtin_exp2f(m1 - mstar) * lds_l[1][l31]
                + __builtin_exp2f(m2 - mstar) * lds_l[2][l31]
                + __builtin_exp2f(m3 - mstar) * lds_l[3][l31];
    float gv = gate[((size_t)b * TT + q) * NHEADS + h];
    float inv = gv / lstar;
    float of0[16], of1[16];
#pragma unroll
    for (int r = 0; r < 16; ++r) {
      of0[r] = o0[r] * myscale + lds_O[0][lane][r]      + lds_O[1][lane][r]      + lds_O[2][lane][r];
      of1[r] = o1[r] * myscale + lds_O[0][lane][16 + r] + lds_O[1][lane][16 + r] + lds_O[2][lane][16 + r];
    }
    unsigned short* orow = attn_out + ((size_t)b * TT + q) * DIMM + h * HDIM;
#pragma unroll
    for (int a2 = 0; a2 < 4; ++a2) {
      int d0 = a2 * 8 + hi * 4;
      union { unsigned short s[4]; uint2 u; } x0, x1;
#pragma unroll
      for (int c = 0; c < 4; ++c) {
        x0.s[c] = f2b(of0[a2 * 4 + c] * inv);
        x1.s[c] = f2b(of1[a2 * 4 + c] * inv);
      }
      *(uint2*)(orow + d0) = x0.u;
      *(uint2*)(orow + 32 + d0) = x1.u;
    }
  }
}

// ---------------- workspace layout (bytes) ----------------
#define OFF_XB    ((size_t)0)
#define OFF_WQKV  ((size_t)8388608)
#define OFF_WO    ((size_t)14680064)
#define OFF_BCAT  ((size_t)16777216)
#define OFF_QKV   ((size_t)16793600)
#define OFF_QR    ((size_t)41959424)
#define OFF_KR    ((size_t)50348032)
#define OFF_VT    ((size_t)58736640)
#define OFF_ATTN  ((size_t)67125248)
#define OFF_GATE  ((size_t)75513856)

extern "C" void kernel_launch(void* const* d_in, const int* in_sizes, int n_in,
                              void* d_out, int out_size, void* d_ws, size_t ws_size,
                              hipStream_t stream) {
  const float* x    = (const float*)d_in[0];
  const float* Wq   = (const float*)d_in[1];
  const float* bq   = (const float*)d_in[2];
  const float* Wk   = (const float*)d_in[3];
  const float* bk   = (const float*)d_in[4];
  const float* Wv   = (const float*)d_in[5];
  const float* bv   = (const float*)d_in[6];
  const float* Wo   = (const float*)d_in[7];
  const float* bo   = (const float*)d_in[8];
  const float* Wg   = (const float*)d_in[9];
  const float* bg   = (const float*)d_in[10];
  const float* cosb = (const float*)d_in[11];
  const float* sinb = (const float*)d_in[12];
  float* out = (float*)d_out;
  char* ws = (char*)d_ws;

  unsigned short* xb    = (unsigned short*)(ws + OFF_XB);
  unsigned short* wqkv  = (unsigned short*)(ws + OFF_WQKV);
  unsigned short* wob   = (unsigned short*)(ws + OFF_WO);
  float*          bcat  = (float*)(ws + OFF_BCAT);
  unsigned short* qkv   = (unsigned short*)(ws + OFF_QKV);
  unsigned short* q_r   = (unsigned short*)(ws + OFF_QR);
  unsigned short* k_r   = (unsigned short*)(ws + OFF_KR);
  unsigned short* v_t   = (unsigned short*)(ws + OFF_VT);
  unsigned short* attn  = (unsigned short*)(ws + OFF_ATTN);
  float*          gateb = (float*)(ws + OFF_GATE);

  prep_kernel<<<8195, 256, 0, stream>>>(x, Wq, Wk, Wv, Wo, bq, bk, bv, xb, wqkv, wob, bcat);
  gate_kernel<<<256, 256, 0, stream>>>(x, Wg, bg, gateb);

  // fused QKV projection: [4096,1024] @ [3072,1024]^T (dbuf 2-phase, swizzled LDS)
  gemm_bt<4, 1><<<dim3(24, 32), 256, 0, stream>>>(xb, wqkv, bcat, qkv, MTOT, 3072, 1024);

  // fused RoPE + V transpose
  ropev_kernel<<<dim3(32, 32), 256, 0, stream>>>(qkv, cosb, sinb, q_r, k_r, v_t);

  // windowed causal flash attention + gate (KVBLK=32, reg-dieted for 4 waves/SIMD)
  attn_kernel<<<2048, 256, 0, stream>>>(q_r, k_r, v_t, gateb, attn);

  // output projection: [4096,1024] @ [1024,1024]^T + bo (dbuf 2-phase)
  gemm_bt<2, 0><<<dim3(8, 64), 256, 0, stream>>>(attn, wob, bo, out, MTOT, 1024, 1024);
}

// Round 13
// 107.215 us; speedup vs baseline: 1.1410x; 1.0043x over previous
//
#include <hip/hip_runtime.h>

#define DIMM 1024
#define NHEADS 16
#define HDIM 64
#define WIN 1024
#define GATEIN 20
#define BB 2
#define TT 2048
#define MTOT (BB*TT)   // 4096

typedef __attribute__((ext_vector_type(8))) short short8;
typedef __attribute__((ext_vector_type(4))) float f32x4;
typedef __attribute__((ext_vector_type(16))) float f32x16;
typedef const __attribute__((address_space(1))) void gvoid_t;
typedef __attribute__((address_space(3))) void lvoid_t;

__device__ __forceinline__ unsigned short f2b(float f) {
  union { float f; unsigned u; } c; c.f = f;
  unsigned u = c.u + 0x7fffu + ((c.u >> 16) & 1u);
  return (unsigned short)(u >> 16);
}
__device__ __forceinline__ float b2f(unsigned short s) {
  union { unsigned u; float f; } c; c.u = ((unsigned)s) << 16;
  return c.f;
}
__device__ __forceinline__ unsigned cvt_pk_bf16(float lo, float hi) {
  unsigned r;
  asm("v_cvt_pk_bf16_f32 %0, %1, %2" : "=v"(r) : "v"(lo), "v"(hi));
  return r;
}
__device__ __forceinline__ float max3f(float a, float b, float c) {
  return fmaxf(fmaxf(a, b), c);   // clang fuses to v_max3_f32
}
// cross-half (lane ^ 32) reductions via permlane32_swap (VALU, no DS)
__device__ __forceinline__ float xmax32(float x) {
  union { float f; unsigned u; } c; c.f = x;
  auto pr = __builtin_amdgcn_permlane32_swap(c.u, c.u, false, false);
  union { unsigned u; float f; } a, b; a.u = pr[0]; b.u = pr[1];
  return fmaxf(a.f, b.f);
}
__device__ __forceinline__ float xsum32(float x) {
  union { float f; unsigned u; } c; c.f = x;
  auto pr = __builtin_amdgcn_permlane32_swap(c.u, c.u, false, false);
  union { unsigned u; float f; } a, b; a.u = pr[0]; b.u = pr[1];
  return a.f + b.f;
}

// ---------------- fused prep: bf16-cast x, Wq|Wk|Wv, Wo; concat biases ----------------
__global__ void prep_kernel(const float* __restrict__ x,  const float* __restrict__ Wq,
                            const float* __restrict__ Wk, const float* __restrict__ Wv,
                            const float* __restrict__ Wo, const float* __restrict__ bq,
                            const float* __restrict__ bk, const float* __restrict__ bv,
                            unsigned short* __restrict__ xb, unsigned short* __restrict__ wqkv,
                            unsigned short* __restrict__ wob, float* __restrict__ bcat) {
  int i = blockIdx.x * blockDim.x + threadIdx.x;
  const float* src; unsigned short* dst; int off;
  if (i < 1048576)      { src = x;  dst = xb;             off = i; }
  else if (i < 1310720) { src = Wq; dst = wqkv;           off = i - 1048576; }
  else if (i < 1572864) { src = Wk; dst = wqkv + 1048576; off = i - 1310720; }
  else if (i < 1835008) { src = Wv; dst = wqkv + 2097152; off = i - 1572864; }
  else if (i < 2097152) { src = Wo; dst = wob;            off = i - 1835008; }
  else {
    int j = i - 2097152;            // 0..767 : bias f32 copy
    if (j < 768) {
      const float* bsrc = (j < 256) ? bq : (j < 512) ? bk : bv;
      int bo = (j & 255) * 4;
      int db = (j < 256) ? 0 : (j < 512) ? 1024 : 2048;
      *(float4*)(bcat + db + bo) = *(const float4*)(bsrc + bo);
    }
    return;
  }
  float4 v = ((const float4*)src)[off];
  union { unsigned short s[4]; uint2 u; } o;
  o.s[0] = f2b(v.x); o.s[1] = f2b(v.y); o.s[2] = f2b(v.z); o.s[3] = f2b(v.w);
  *(uint2*)(dst + (size_t)off * 4) = o.u;
}

// ---------------- gate = sigmoid(x[:, :20] @ Wg^T + bg), [M][H] f32 ----------------
__global__ void gate_kernel(const float* __restrict__ x, const float* __restrict__ Wg,
                            const float* __restrict__ bg, float* __restrict__ gate) {
  int i = blockIdx.x * blockDim.x + threadIdx.x;   // M*H
  if (i >= MTOT * NHEADS) return;
  int h = i & 15;
  int m = i >> 4;
  const float* xr = x + (size_t)m * DIMM;
  const float* wr = Wg + h * GATEIN;
  float z = bg[h];
#pragma unroll
  for (int g = 0; g < GATEIN; ++g) z += xr[g] * wr[g];
  gate[i] = 1.f / (1.f + __expf(-z));
}

// ---------------- GEMM: C[M,N] = A[M,K] @ Bw[N,K]^T + bias ----------------
// Tile = (MF*32) x 128, 4 waves. LDS XOR-swizzle (T2) + double-buffered 2-phase.
template<int MF, int OUTBF>
__global__ __launch_bounds__(256) void gemm_bt(const unsigned short* __restrict__ A,
                                               const unsigned short* __restrict__ Bw,
                                               const float* __restrict__ bias,
                                               void* __restrict__ Cout,
                                               int M, int N, int K) {
  __shared__ __align__(16) unsigned short As[2][MF * 32 * 32];
  __shared__ __align__(16) unsigned short Bs[2][128 * 32];
  const int tid = threadIdx.x;
  const int lane = tid & 63, wid = tid >> 6;
  const int g = lane >> 4, r16 = lane & 15;
  const int m0 = blockIdx.y * (MF * 32), n0 = blockIdx.x * 128;
  const int wr = (wid >> 1) * (MF * 16), wc = (wid & 1) * 64;
  const int wbase = wid * 64;

  int oaf[MF], obf[4];
#pragma unroll
  for (int mf = 0; mf < MF; ++mf) {
    int row = wr + mf * 16 + r16;
    oaf[mf] = row * 32 + ((g ^ ((row >> 1) & 3)) * 8);
  }
#pragma unroll
  for (int nf = 0; nf < 4; ++nf) {
    int row = wc + nf * 16 + r16;
    obf[nf] = row * 32 + ((g ^ ((row >> 1) & 3)) * 8);
  }

  f32x4 acc[MF][4];
#pragma unroll
  for (int i = 0; i < MF; ++i)
#pragma unroll
    for (int j = 0; j < 4; ++j) acc[i][j] = (f32x4){0.f, 0.f, 0.f, 0.f};

  auto stage = [&](int buf, int k0) {
#pragma unroll
    for (int j = 0; j < MF / 2; ++j) {
      int sbase = j * 256 + wbase;
      int s = sbase + lane;
      int l = s ^ ((s >> 3) & 3);
      const unsigned short* gA = A + (size_t)(m0 + (l >> 2)) * K + k0 + (l & 3) * 8;
      __builtin_amdgcn_global_load_lds((gvoid_t*)gA,
          (lvoid_t*)((char*)&As[buf][0] + sbase * 16), 16, 0, 0);
    }
#pragma unroll
    for (int j = 0; j < 2; ++j) {
      int sbase = j * 256 + wbase;
      int s = sbase + lane;
      int l = s ^ ((s >> 3) & 3);
      const unsigned short* gB = Bw + (size_t)(n0 + (l >> 2)) * K + k0 + (l & 3) * 8;
      __builtin_amdgcn_global_load_lds((gvoid_t*)gB,
          (lvoid_t*)((char*)&Bs[buf][0] + sbase * 16), 16, 0, 0);
    }
  };

  const int NT = K >> 5;
  stage(0, 0);
  __syncthreads();
  for (int t = 0; t < NT; ++t) {
    const int buf = t & 1;
    if (t + 1 < NT) stage(buf ^ 1, (t + 1) << 5);   // prefetch next tile
    short8 af[MF], bf[4];
#pragma unroll
    for (int mf = 0; mf < MF; ++mf) af[mf] = *(const short8*)(&As[buf][0] + oaf[mf]);
#pragma unroll
    for (int nf = 0; nf < 4; ++nf)  bf[nf] = *(const short8*)(&Bs[buf][0] + obf[nf]);
#pragma unroll
    for (int mf = 0; mf < MF; ++mf)
#pragma unroll
      for (int nf = 0; nf < 4; ++nf)
        acc[mf][nf] = __builtin_amdgcn_mfma_f32_16x16x32_bf16(af[mf], bf[nf], acc[mf][nf], 0, 0, 0);
    __syncthreads();   // drains prefetch (post-compute) + guards buf reuse
  }
#pragma unroll
  for (int mf = 0; mf < MF; ++mf)
#pragma unroll
    for (int nf = 0; nf < 4; ++nf)
#pragma unroll
      for (int rr = 0; rr < 4; ++rr) {
        int m = m0 + wr + mf * 16 + g * 4 + rr;
        int n = n0 + wc + nf * 16 + r16;
        float v = acc[mf][nf][rr] + bias[n];
        if (OUTBF) ((unsigned short*)Cout)[(size_t)m * N + n] = f2b(v);
        else       ((float*)Cout)[(size_t)m * N + n] = v;
      }
}

// ---------------- fused RoPE (q,k) + V transpose ----------------
#define QSCALE (0.125f * 1.4426950408889634f)
__global__ __launch_bounds__(256) void ropev_kernel(const unsigned short* __restrict__ qkv,
                                                    const float* __restrict__ cosb,
                                                    const float* __restrict__ sinb,
                                                    unsigned short* __restrict__ qr,
                                                    unsigned short* __restrict__ kr,
                                                    unsigned short* __restrict__ vt) {
  __shared__ unsigned short tile[64][66];
  const int t0 = blockIdx.x * 64;
  const int bh = blockIdx.y;
  const int b = bh >> 4, h = bh & 15;
  const int tid = threadIdx.x;
  const int tr = tid >> 2;          // 0..63 (row within tile)
  const int qd = tid & 3;           // quarter
  const int t = t0 + tr;
  const size_t base = (size_t)bh * TT * HDIM;
  const unsigned short* row = qkv + (size_t)(b * TT + t) * 3072 + h * 64;

  {
    const unsigned short* vsrc = row + 2048 + qd * 16;
    short8 v0 = *(const short8*)vsrc;
    short8 v1 = *(const short8*)(vsrc + 8);
#pragma unroll
    for (int j = 0; j < 8; ++j) {
      tile[tr][qd * 16 + j]     = (unsigned short)v0[j];
      tile[tr][qd * 16 + 8 + j] = (unsigned short)v1[j];
    }
  }

  {
    const int d0 = qd * 8;
    short8 q1 = *(const short8*)(row + d0);
    short8 q2 = *(const short8*)(row + d0 + 32);
    short8 k1 = *(const short8*)(row + 1024 + d0);
    short8 k2 = *(const short8*)(row + 1024 + d0 + 32);
    float4 c0 = *(const float4*)(cosb + t * 32 + d0);
    float4 c1 = *(const float4*)(cosb + t * 32 + d0 + 4);
    float4 s0 = *(const float4*)(sinb + t * 32 + d0);
    float4 s1 = *(const float4*)(sinb + t * 32 + d0 + 4);
    float cc[8] = {c0.x, c0.y, c0.z, c0.w, c1.x, c1.y, c1.z, c1.w};
    float ss[8] = {s0.x, s0.y, s0.z, s0.w, s1.x, s1.y, s1.z, s1.w};
    short8 qo1, qo2, ko1, ko2;
#pragma unroll
    for (int j = 0; j < 8; ++j) {
      float a1 = b2f((unsigned short)q1[j]), a2 = b2f((unsigned short)q2[j]);
      float b1 = b2f((unsigned short)k1[j]), b2v = b2f((unsigned short)k2[j]);
      qo1[j] = (short)f2b((a1 * cc[j] - a2 * ss[j]) * QSCALE);
      qo2[j] = (short)f2b((a1 * ss[j] + a2 * cc[j]) * QSCALE);
      ko1[j] = (short)f2b(b1 * cc[j] - b2v * ss[j]);
      ko2[j] = (short)f2b(b1 * ss[j] + b2v * cc[j]);
    }
    *(short8*)(qr + base + (size_t)t * HDIM + d0)      = qo1;
    *(short8*)(qr + base + (size_t)t * HDIM + d0 + 32) = qo2;
    size_t ok = base + (size_t)(t >> 5) * 2048 + (size_t)(qd >> 1) * 512
              + (size_t)(qd & 1) * 256 + (size_t)(t & 31) * 8;
    *(short8*)(kr + ok)        = ko1;
    *(short8*)(kr + ok + 1024) = ko2;   // d+32 -> st+2
  }
  __syncthreads();

  {
    const int d = tid >> 2;           // 0..63
    const int tc = (tid & 3) * 16;    // key chunk of 16
    short8 o0, o1;
#pragma unroll
    for (int j = 0; j < 8; ++j) {
      o0[j] = (short)tile[tc + j][d];
      o1[j] = (short)tile[tc + 8 + j][d];
    }
    int kt = (t0 + tc) >> 5;
    int n  = (tc >> 4) & 1;
    int m  = d >> 5, l31v = d & 31;
    size_t A0 = base + (size_t)kt * 2048 + (size_t)(m * 2 + n) * 512 + (size_t)l31v * 8;
    *(short8*)(vt + A0)       = o0;
    *(short8*)(vt + A0 + 256) = o1;
  }
}

// ---------------- flash attention: 4-way split-KV, KVBLK=32, swapped QK^T ----------------
// R11: register-dieted R9 structure targeting <=128 unified regs -> 4 waves/SIMD
// (m69 bracket). Cuts vs R9: no ones-MFMA row-sum (VALU tree instead, -36 regs),
// V loads moved after softmax (-16 peak-live). __launch_bounds__(256,4) enforces.
__global__ __launch_bounds__(256, 4) void attn_kernel(const unsigned short* __restrict__ qr,
                                                      const unsigned short* __restrict__ kr,
                                                      const unsigned short* __restrict__ vt,
                                                      const float* __restrict__ gate,
                                                      unsigned short* __restrict__ attn_out) {
  __shared__ float lds_m[4][32];
  __shared__ float lds_l[4][32];
  __shared__ float lds_O[3][64][33];
  const int tid = threadIdx.x;
  const int lane = tid & 63, wid = tid >> 6;
  const int l31 = lane & 31, hi = lane >> 5;

  const int fid = blockIdx.x;
  const int idx = fid >> 3;                 // 0..255
  const int bh = (fid & 7) * 4 + (idx & 3);
  const int qt = 63 - (idx >> 2);
  const int q0 = qt * 32;
  const int b = bh >> 4, h = bh & 15;
  const unsigned short* kptr = kr + (size_t)bh * TT * HDIM;
  const unsigned short* vptr = vt + (size_t)bh * TT * HDIM;
  const int q = q0 + l31;

  short8 qf[4];
#pragma unroll
  for (int st = 0; st < 4; ++st)
    qf[st] = *(const short8*)(qr + (size_t)bh * TT * HDIM + (size_t)q * HDIM + st * 16 + hi * 8);

  f32x16 o0, o1;
#pragma unroll
  for (int r = 0; r < 16; ++r) { o0[r] = 0.f; o1[r] = 0.f; }
  float mrun = -1e30f, lrun = 0.f;

  int kv_lo = q0 - WIN;
  if (kv_lo < 0) kv_lo = 0;
  const int kv_hi = q0 + 32;

  for (int kv = kv_lo + wid * 32; kv < kv_hi; kv += 128) {
    const unsigned short* kf = kptr + (size_t)kv * 64 + lane * 8;
    short8 k0 = *(const short8*)(kf);
    short8 k1 = *(const short8*)(kf + 512);
    short8 k2 = *(const short8*)(kf + 1024);
    short8 k3 = *(const short8*)(kf + 1536);

    f32x16 s;
#pragma unroll
    for (int r = 0; r < 16; ++r) s[r] = 0.f;
    s = __builtin_amdgcn_mfma_f32_32x32x16_bf16(k0, qf[0], s, 0, 0, 0);
    s = __builtin_amdgcn_mfma_f32_32x32x16_bf16(k1, qf[1], s, 0, 0, 0);
    s = __builtin_amdgcn_mfma_f32_32x32x16_bf16(k2, qf[2], s, 0, 0, 0);
    s = __builtin_amdgcn_mfma_f32_32x32x16_bf16(k3, qf[3], s, 0, 0, 0);

    // masks only on peeled steps (wave-uniform branches), in place
    if (kv == q0) {
#pragma unroll
      for (int r = 0; r < 16; ++r) {
        int key = kv + (r & 3) + 8 * (r >> 2) + 4 * hi;
        s[r] = (key <= q) ? s[r] : -1e30f;
      }
    } else if (q0 >= WIN && kv == kv_lo) {
#pragma unroll
      for (int r = 0; r < 16; ++r) {
        int key = kv + (r & 3) + 8 * (r >> 2) + 4 * hi;
        s[r] = (key + WIN >= q) ? s[r] : -1e30f;
      }
    }

    // row-max: max3 tree (depth 3) + cross-half swap
    float t0 = max3f(s[0],  s[1],  s[2]);
    float t1 = max3f(s[3],  s[4],  s[5]);
    float t2 = max3f(s[6],  s[7],  s[8]);
    float t3 = max3f(s[9],  s[10], s[11]);
    float t4 = max3f(s[12], s[13], s[14]);
    float lm = fmaxf(max3f(t0, t1, t2), max3f(t3, t4, s[15]));
    lm = xmax32(lm);

    if (!__all(lm - mrun <= 8.f)) {
      float mnew = fmaxf(mrun, lm);
      float scf = __builtin_exp2f(mrun - mnew);
      mrun = mnew;
      lrun *= scf;
#pragma unroll
      for (int r = 0; r < 16; ++r) { o0[r] *= scf; o1[r] *= scf; }
    }

    // P = exp2(s - mrun) in place; masked entries underflow to 0
#pragma unroll
    for (int r = 0; r < 16; ++r) s[r] = __builtin_exp2f(s[r] - mrun);

    // row-sum: pair-add tree + cross-half swap (replaces R9's ones-MFMA; -36 regs)
    float c0 = (s[0] + s[1]) + (s[2] + s[3]);
    float c1 = (s[4] + s[5]) + (s[6] + s[7]);
    float c2 = (s[8] + s[9]) + (s[10] + s[11]);
    float c3 = (s[12] + s[13]) + (s[14] + s[15]);
    lrun += xsum32((c0 + c1) + (c2 + c3));

    // P -> bf16 B-frags: cvt_pk + permlane32_swap (T12)
    unsigned w0 = cvt_pk_bf16(s[0],  s[1]),  w1 = cvt_pk_bf16(s[2],  s[3]);
    unsigned w2 = cvt_pk_bf16(s[4],  s[5]),  w3 = cvt_pk_bf16(s[6],  s[7]);
    unsigned w4 = cvt_pk_bf16(s[8],  s[9]),  w5 = cvt_pk_bf16(s[10], s[11]);
    unsigned w6 = cvt_pk_bf16(s[12], s[13]), w7 = cvt_pk_bf16(s[14], s[15]);
    auto s1p = __builtin_amdgcn_permlane32_swap(w0, w2, false, false);
    auto s2p = __builtin_amdgcn_permlane32_swap(w1, w3, false, false);
    auto s3p = __builtin_amdgcn_permlane32_swap(w4, w6, false, false);
    auto s4p = __builtin_amdgcn_permlane32_swap(w5, w7, false, false);
    union { unsigned u[4]; short8 s8; } pf0, pf1;
    pf0.u[0] = s1p[0]; pf0.u[1] = s2p[0]; pf0.u[2] = s1p[1]; pf0.u[3] = s2p[1];
    pf1.u[0] = s3p[0]; pf1.u[1] = s4p[0]; pf1.u[2] = s3p[1]; pf1.u[3] = s4p[1];

    // V loads after softmax (peak-live reduction; TLP at 4 waves/SIMD hides latency)
    const unsigned short* vf = vptr + (size_t)kv * 64 + lane * 8;
    short8 vf00 = *(const short8*)(vf);
    short8 vf01 = *(const short8*)(vf + 512);
    short8 vf10 = *(const short8*)(vf + 1024);
    short8 vf11 = *(const short8*)(vf + 1536);

    o0 = __builtin_amdgcn_mfma_f32_32x32x16_bf16(vf00, pf0.s8, o0, 0, 0, 0);
    o1 = __builtin_amdgcn_mfma_f32_32x32x16_bf16(vf10, pf0.s8, o1, 0, 0, 0);
    o0 = __builtin_amdgcn_mfma_f32_32x32x16_bf16(vf01, pf1.s8, o0, 0, 0, 0);
    o1 = __builtin_amdgcn_mfma_f32_32x32x16_bf16(vf11, pf1.s8, o1, 0, 0, 0);
  }

  // ---- combine across the 4 waves ----
  if (hi == 0) { lds_m[wid][l31] = mrun; lds_l[wid][l31] = lrun; }
  __syncthreads();
  float m0 = lds_m[0][l31], m1 = lds_m[1][l31], m2 = lds_m[2][l31], m3 = lds_m[3][l31];
  float mstar = fmaxf(fmaxf(m0, m1), fmaxf(m2, m3));
  float myscale = __builtin_exp2f(mrun - mstar);
  if (wid != 0) {
#pragma unroll
    for (int r = 0; r < 16; ++r) {
      lds_O[wid - 1][lane][r]      = o0[r] * myscale;
      lds_O[wid - 1][lane][16 + r] = o1[r] * myscale;
    }
  }
  __syncthreads();
  if (wid == 0) {
    float lstar = __builtin_exp2f(m0 - mstar) * lds_l[0][l31]
                + __builtin_exp2f(m1 - mstar) * lds_l[1][l31]
                + __builtin_exp2f(m2 - mstar) * lds_l[2][l31]
                + __builtin_exp2f(m3 - mstar) * lds_l[3][l31];
    float gv = gate[((size_t)b * TT + q) * NHEADS + h];
    float inv = gv / lstar;
    float of0[16], of1[16];
#pragma unroll
    for (int r = 0; r < 16; ++r) {
      of0[r] = o0[r] * myscale + lds_O[0][lane][r]      + lds_O[1][lane][r]      + lds_O[2][lane][r];
      of1[r] = o1[r] * myscale + lds_O[0][lane][16 + r] + lds_O[1][lane][16 + r] + lds_O[2][lane][16 + r];
    }
    unsigned short* orow = attn_out + ((size_t)b * TT + q) * DIMM + h * HDIM;
#pragma unroll
    for (int a2 = 0; a2 < 4; ++a2) {
      int d0 = a2 * 8 + hi * 4;
      union { unsigned short s[4]; uint2 u; } x0, x1;
#pragma unroll
      for (int c = 0; c < 4; ++c) {
        x0.s[c] = f2b(of0[a2 * 4 + c] * inv);
        x1.s[c] = f2b(of1[a2 * 4 + c] * inv);
      }
      *(uint2*)(orow + d0) = x0.u;
      *(uint2*)(orow + 32 + d0) = x1.u;
    }
  }
}

// ---------------- workspace layout (bytes) ----------------
#define OFF_XB    ((size_t)0)
#define OFF_WQKV  ((size_t)8388608)
#define OFF_WO    ((size_t)14680064)
#define OFF_BCAT  ((size_t)16777216)
#define OFF_QKV   ((size_t)16793600)
#define OFF_QR    ((size_t)41959424)
#define OFF_KR    ((size_t)50348032)
#define OFF_VT    ((size_t)58736640)
#define OFF_ATTN  ((size_t)67125248)
#define OFF_GATE  ((size_t)75513856)

extern "C" void kernel_launch(void* const* d_in, const int* in_sizes, int n_in,
                              void* d_out, int out_size, void* d_ws, size_t ws_size,
                              hipStream_t stream) {
  const float* x    = (const float*)d_in[0];
  const float* Wq   = (const float*)d_in[1];
  const float* bq   = (const float*)d_in[2];
  const float* Wk   = (const float*)d_in[3];
  const float* bk   = (const float*)d_in[4];
  const float* Wv   = (const float*)d_in[5];
  const float* bv   = (const float*)d_in[6];
  const float* Wo   = (const float*)d_in[7];
  const float* bo   = (const float*)d_in[8];
  const float* Wg   = (const float*)d_in[9];
  const float* bg   = (const float*)d_in[10];
  const float* cosb = (const float*)d_in[11];
  const float* sinb = (const float*)d_in[12];
  float* out = (float*)d_out;
  char* ws = (char*)d_ws;

  unsigned short* xb    = (unsigned short*)(ws + OFF_XB);
  unsigned short* wqkv  = (unsigned short*)(ws + OFF_WQKV);
  unsigned short* wob   = (unsigned short*)(ws + OFF_WO);
  float*          bcat  = (float*)(ws + OFF_BCAT);
  unsigned short* qkv   = (unsigned short*)(ws + OFF_QKV);
  unsigned short* q_r   = (unsigned short*)(ws + OFF_QR);
  unsigned short* k_r   = (unsigned short*)(ws + OFF_KR);
  unsigned short* v_t   = (unsigned short*)(ws + OFF_VT);
  unsigned short* attn  = (unsigned short*)(ws + OFF_ATTN);
  float*          gateb = (float*)(ws + OFF_GATE);

  prep_kernel<<<8195, 256, 0, stream>>>(x, Wq, Wk, Wv, Wo, bq, bk, bv, xb, wqkv, wob, bcat);
  gate_kernel<<<256, 256, 0, stream>>>(x, Wg, bg, gateb);

  // fused QKV projection: [4096,1024] @ [3072,1024]^T (dbuf 2-phase, swizzled LDS)
  gemm_bt<4, 1><<<dim3(24, 32), 256, 0, stream>>>(xb, wqkv, bcat, qkv, MTOT, 3072, 1024);

  // fused RoPE + V transpose
  ropev_kernel<<<dim3(32, 32), 256, 0, stream>>>(qkv, cosb, sinb, q_r, k_r, v_t);

  // windowed causal flash attention + gate (KVBLK=32, reg-dieted for 4 waves/SIMD)
  attn_kernel<<<2048, 256, 0, stream>>>(q_r, k_r, v_t, gateb, attn);

  // output projection: [4096,1024] @ [1024,1024]^T + bo (dbuf 2-phase)
  gemm_bt<2, 0><<<dim3(8, 64), 256, 0, stream>>>(attn, wob, bo, out, MTOT, 1024, 1024);
}

// Round 14
// 106.423 us; speedup vs baseline: 1.1495x; 1.0074x over previous
//
#include <hip/hip_runtime.h>

#define DIMM 1024
#define NHEADS 16
#define HDIM 64
#define WIN 1024
#define GATEIN 20
#define BB 2
#define TT 2048
#define MTOT (BB*TT)   // 4096

typedef __attribute__((ext_vector_type(8))) short short8;
typedef __attribute__((ext_vector_type(4))) float f32x4;
typedef __attribute__((ext_vector_type(16))) float f32x16;
typedef const __attribute__((address_space(1))) void gvoid_t;
typedef __attribute__((address_space(3))) void lvoid_t;

__device__ __forceinline__ unsigned short f2b(float f) {
  union { float f; unsigned u; } c; c.f = f;
  unsigned u = c.u + 0x7fffu + ((c.u >> 16) & 1u);
  return (unsigned short)(u >> 16);
}
__device__ __forceinline__ float b2f(unsigned short s) {
  union { unsigned u; float f; } c; c.u = ((unsigned)s) << 16;
  return c.f;
}
__device__ __forceinline__ unsigned cvt_pk_bf16(float lo, float hi) {
  unsigned r;
  asm("v_cvt_pk_bf16_f32 %0, %1, %2" : "=v"(r) : "v"(lo), "v"(hi));
  return r;
}
__device__ __forceinline__ float max3f(float a, float b, float c) {
  return fmaxf(fmaxf(a, b), c);   // clang fuses to v_max3_f32
}
// cross-half (lane ^ 32) reductions via permlane32_swap (VALU, no DS)
__device__ __forceinline__ float xmax32(float x) {
  union { float f; unsigned u; } c; c.f = x;
  auto pr = __builtin_amdgcn_permlane32_swap(c.u, c.u, false, false);
  union { unsigned u; float f; } a, b; a.u = pr[0]; b.u = pr[1];
  return fmaxf(a.f, b.f);
}
__device__ __forceinline__ float xsum32(float x) {
  union { float f; unsigned u; } c; c.f = x;
  auto pr = __builtin_amdgcn_permlane32_swap(c.u, c.u, false, false);
  union { unsigned u; float f; } a, b; a.u = pr[0]; b.u = pr[1];
  return a.f + b.f;
}

#define QSCALE (0.125f * 1.4426950408889634f)

// ---------------- fused prep: bf16-cast x, Wq|Wk|Wv, Wo; concat biases ----------------
__global__ void prep_kernel(const float* __restrict__ x,  const float* __restrict__ Wq,
                            const float* __restrict__ Wk, const float* __restrict__ Wv,
                            const float* __restrict__ Wo, const float* __restrict__ bq,
                            const float* __restrict__ bk, const float* __restrict__ bv,
                            unsigned short* __restrict__ xb, unsigned short* __restrict__ wqkv,
                            unsigned short* __restrict__ wob, float* __restrict__ bcat) {
  int i = blockIdx.x * blockDim.x + threadIdx.x;
  const float* src; unsigned short* dst; int off;
  if (i < 1048576)      { src = x;  dst = xb;             off = i; }
  else if (i < 1310720) { src = Wq; dst = wqkv;           off = i - 1048576; }
  else if (i < 1572864) { src = Wk; dst = wqkv + 1048576; off = i - 1310720; }
  else if (i < 1835008) { src = Wv; dst = wqkv + 2097152; off = i - 1572864; }
  else if (i < 2097152) { src = Wo; dst = wob;            off = i - 1835008; }
  else {
    int j = i - 2097152;            // 0..767 : bias f32 copy
    if (j < 768) {
      const float* bsrc = (j < 256) ? bq : (j < 512) ? bk : bv;
      int bo = (j & 255) * 4;
      int db = (j < 256) ? 0 : (j < 512) ? 1024 : 2048;
      *(float4*)(bcat + db + bo) = *(const float4*)(bsrc + bo);
    }
    return;
  }
  float4 v = ((const float4*)src)[off];
  union { unsigned short s[4]; uint2 u; } o;
  o.s[0] = f2b(v.x); o.s[1] = f2b(v.y); o.s[2] = f2b(v.z); o.s[3] = f2b(v.w);
  *(uint2*)(dst + (size_t)off * 4) = o.u;
}

// ---------------- gate = sigmoid(x[:, :20] @ Wg^T + bg), [M][H] f32 ----------------
__global__ void gate_kernel(const float* __restrict__ x, const float* __restrict__ Wg,
                            const float* __restrict__ bg, float* __restrict__ gate) {
  int i = blockIdx.x * blockDim.x + threadIdx.x;   // M*H
  if (i >= MTOT * NHEADS) return;
  int h = i & 15;
  int m = i >> 4;
  const float* xr = x + (size_t)m * DIMM;
  const float* wr = Wg + h * GATEIN;
  float z = bg[h];
#pragma unroll
  for (int g = 0; g < GATEIN; ++g) z += xr[g] * wr[g];
  gate[i] = 1.f / (1.f + __expf(-z));
}

// ---------------- QKV GEMM with fused RoPE + relayout epilogue ----------------
// 128x128 tile, 4 waves, swizzled LDS, dbuf 2-phase. N=3072 = [q|k|v].
// Epilogue (block-uniform seg select): q -> row-major [bh][t][64] * QSCALE;
// k -> frag order (RoPE'd); v -> frag order. Kills the 25MB qkv intermediate.
// RoPE pair (d, d+32) = acc[mf][nf] / acc[mf][nf+2] (same thread).
__global__ __launch_bounds__(256) void gemm_qkv(const unsigned short* __restrict__ A,
                                                const unsigned short* __restrict__ Bw,
                                                const float* __restrict__ bias,
                                                const float* __restrict__ cosb,
                                                const float* __restrict__ sinb,
                                                unsigned short* __restrict__ qr,
                                                unsigned short* __restrict__ kr,
                                                unsigned short* __restrict__ vt) {
  const int M = MTOT, N = 3072, K = DIMM;
  __shared__ __align__(16) unsigned short As[2][128 * 32];
  __shared__ __align__(16) unsigned short Bs[2][128 * 32];
  const int tid = threadIdx.x;
  const int lane = tid & 63, wid = tid >> 6;
  const int g = lane >> 4, r16 = lane & 15;
  const int m0 = blockIdx.y * 128, n0 = blockIdx.x * 128;
  const int wr = (wid >> 1) * 64, wc = (wid & 1) * 64;
  const int wbase = wid * 64;

  int oaf[4], obf[4];
#pragma unroll
  for (int mf = 0; mf < 4; ++mf) {
    int row = wr + mf * 16 + r16;
    oaf[mf] = row * 32 + ((g ^ ((row >> 1) & 3)) * 8);
  }
#pragma unroll
  for (int nf = 0; nf < 4; ++nf) {
    int row = wc + nf * 16 + r16;
    obf[nf] = row * 32 + ((g ^ ((row >> 1) & 3)) * 8);
  }

  f32x4 acc[4][4];
#pragma unroll
  for (int i = 0; i < 4; ++i)
#pragma unroll
    for (int j = 0; j < 4; ++j) acc[i][j] = (f32x4){0.f, 0.f, 0.f, 0.f};

  auto stage = [&](int buf, int k0) {
#pragma unroll
    for (int j = 0; j < 2; ++j) {
      int sbase = j * 256 + wbase;
      int s = sbase + lane;
      int l = s ^ ((s >> 3) & 3);
      const unsigned short* gA = A + (size_t)(m0 + (l >> 2)) * K + k0 + (l & 3) * 8;
      __builtin_amdgcn_global_load_lds((gvoid_t*)gA,
          (lvoid_t*)((char*)&As[buf][0] + sbase * 16), 16, 0, 0);
      const unsigned short* gB = Bw + (size_t)(n0 + (l >> 2)) * K + k0 + (l & 3) * 8;
      __builtin_amdgcn_global_load_lds((gvoid_t*)gB,
          (lvoid_t*)((char*)&Bs[buf][0] + sbase * 16), 16, 0, 0);
    }
  };

  const int NT = K >> 5;
  stage(0, 0);
  __syncthreads();
  for (int t = 0; t < NT; ++t) {
    const int buf = t & 1;
    if (t + 1 < NT) stage(buf ^ 1, (t + 1) << 5);
    short8 af[4], bf[4];
#pragma unroll
    for (int mf = 0; mf < 4; ++mf) af[mf] = *(const short8*)(&As[buf][0] + oaf[mf]);
#pragma unroll
    for (int nf = 0; nf < 4; ++nf)  bf[nf] = *(const short8*)(&Bs[buf][0] + obf[nf]);
#pragma unroll
    for (int mf = 0; mf < 4; ++mf)
#pragma unroll
      for (int nf = 0; nf < 4; ++nf)
        acc[mf][nf] = __builtin_amdgcn_mfma_f32_16x16x32_bf16(af[mf], bf[nf], acc[mf][nf], 0, 0, 0);
    __syncthreads();
  }

  // ---- fused epilogue ----
  const int ncol = n0 + wc;                 // multiple of 64
  const int seg  = ncol >> 10;              // 0=q 1=k 2=v
  const int h    = (ncol >> 6) & 15;
  const int bb   = m0 >> 11;                // batch (block never crosses 2048)
  const int tb   = (m0 + wr) & 2047;        // wave's first t (mult of 64)
  const size_t base = (size_t)(bb * NHEADS + h) * TT * HDIM;
  float bias_v[4];
#pragma unroll
  for (int nf = 0; nf < 4; ++nf) bias_v[nf] = bias[ncol + nf * 16 + r16];

  if (seg == 2) {
    // V: frag order; per (mf,nf) the 4 rr are consecutive shorts -> one uint2
#pragma unroll
    for (int mf = 0; mf < 4; ++mf) {
      int kvt = (tb >> 5) + (mf >> 1);
#pragma unroll
      for (int nf = 0; nf < 4; ++nf) {
        union { unsigned short s4[4]; uint2 u; } w;
#pragma unroll
        for (int rr = 0; rr < 4; ++rr) w.s4[rr] = f2b(acc[mf][nf][rr] + bias_v[nf]);
        size_t addr = base + (size_t)kvt * 2048
                    + (size_t)((nf >> 1) * 2 + (mf & 1)) * 512
                    + (size_t)(g >> 1) * 256
                    + (size_t)((nf & 1) * 16 + r16) * 8 + 4 * (g & 1);
        *(uint2*)(vt + addr) = w.u;
      }
    }
  } else {
    // Q / K: RoPE pairs (nf, nf+2)
#pragma unroll
    for (int mf = 0; mf < 4; ++mf) {
#pragma unroll
      for (int rr = 0; rr < 4; ++rr) {
        int t = tb + mf * 16 + g * 4 + rr;
#pragma unroll
        for (int nf = 0; nf < 2; ++nf) {
          int d = nf * 16 + r16;
          float c = cosb[t * 32 + d], s = sinb[t * 32 + d];
          float v1 = acc[mf][nf][rr]     + bias_v[nf];
          float v2 = acc[mf][nf + 2][rr] + bias_v[nf + 2];
          float o1 = v1 * c - v2 * s;
          float o2 = v1 * s + v2 * c;
          if (seg == 0) {
            qr[base + (size_t)t * HDIM + d]      = f2b(o1 * QSCALE);
            qr[base + (size_t)t * HDIM + d + 32] = f2b(o2 * QSCALE);
          } else {
            size_t ok = base + (size_t)(t >> 5) * 2048 + (size_t)nf * 512
                      + (size_t)(r16 >> 3) * 256 + (size_t)(t & 31) * 8 + (r16 & 7);
            kr[ok]        = f2b(o1);
            kr[ok + 1024] = f2b(o2);   // d+32 -> st+2
          }
        }
      }
    }
  }
}

// ---------------- out-proj GEMM: C[M,N] = A[M,K] @ Bw[N,K]^T + bias (f32 out) ----------------
template<int MF>
__global__ __launch_bounds__(256) void gemm_bt(const unsigned short* __restrict__ A,
                                               const unsigned short* __restrict__ Bw,
                                               const float* __restrict__ bias,
                                               float* __restrict__ Cout,
                                               int M, int N, int K) {
  __shared__ __align__(16) unsigned short As[2][MF * 32 * 32];
  __shared__ __align__(16) unsigned short Bs[2][128 * 32];
  const int tid = threadIdx.x;
  const int lane = tid & 63, wid = tid >> 6;
  const int g = lane >> 4, r16 = lane & 15;
  const int m0 = blockIdx.y * (MF * 32), n0 = blockIdx.x * 128;
  const int wr = (wid >> 1) * (MF * 16), wc = (wid & 1) * 64;
  const int wbase = wid * 64;

  int oaf[MF], obf[4];
#pragma unroll
  for (int mf = 0; mf < MF; ++mf) {
    int row = wr + mf * 16 + r16;
    oaf[mf] = row * 32 + ((g ^ ((row >> 1) & 3)) * 8);
  }
#pragma unroll
  for (int nf = 0; nf < 4; ++nf) {
    int row = wc + nf * 16 + r16;
    obf[nf] = row * 32 + ((g ^ ((row >> 1) & 3)) * 8);
  }

  f32x4 acc[MF][4];
#pragma unroll
  for (int i = 0; i < MF; ++i)
#pragma unroll
    for (int j = 0; j < 4; ++j) acc[i][j] = (f32x4){0.f, 0.f, 0.f, 0.f};

  auto stage = [&](int buf, int k0) {
#pragma unroll
    for (int j = 0; j < MF / 2; ++j) {
      int sbase = j * 256 + wbase;
      int s = sbase + lane;
      int l = s ^ ((s >> 3) & 3);
      const unsigned short* gA = A + (size_t)(m0 + (l >> 2)) * K + k0 + (l & 3) * 8;
      __builtin_amdgcn_global_load_lds((gvoid_t*)gA,
          (lvoid_t*)((char*)&As[buf][0] + sbase * 16), 16, 0, 0);
    }
#pragma unroll
    for (int j = 0; j < 2; ++j) {
      int sbase = j * 256 + wbase;
      int s = sbase + lane;
      int l = s ^ ((s >> 3) & 3);
      const unsigned short* gB = Bw + (size_t)(n0 + (l >> 2)) * K + k0 + (l & 3) * 8;
      __builtin_amdgcn_global_load_lds((gvoid_t*)gB,
          (lvoid_t*)((char*)&Bs[buf][0] + sbase * 16), 16, 0, 0);
    }
  };

  const int NT = K >> 5;
  stage(0, 0);
  __syncthreads();
  for (int t = 0; t < NT; ++t) {
    const int buf = t & 1;
    if (t + 1 < NT) stage(buf ^ 1, (t + 1) << 5);
    short8 af[MF], bf[4];
#pragma unroll
    for (int mf = 0; mf < MF; ++mf) af[mf] = *(const short8*)(&As[buf][0] + oaf[mf]);
#pragma unroll
    for (int nf = 0; nf < 4; ++nf)  bf[nf] = *(const short8*)(&Bs[buf][0] + obf[nf]);
#pragma unroll
    for (int mf = 0; mf < MF; ++mf)
#pragma unroll
      for (int nf = 0; nf < 4; ++nf)
        acc[mf][nf] = __builtin_amdgcn_mfma_f32_16x16x32_bf16(af[mf], bf[nf], acc[mf][nf], 0, 0, 0);
    __syncthreads();
  }
#pragma unroll
  for (int mf = 0; mf < MF; ++mf)
#pragma unroll
    for (int nf = 0; nf < 4; ++nf)
#pragma unroll
      for (int rr = 0; rr < 4; ++rr) {
        int m = m0 + wr + mf * 16 + g * 4 + rr;
        int n = n0 + wc + nf * 16 + r16;
        Cout[(size_t)m * N + n] = acc[mf][nf][rr] + bias[n];
      }
}

// ---------------- flash attention: 4-way split-KV, KVBLK=32, swapped QK^T ----------------
// Register-dieted for 4 waves/SIMD (<=128 unified regs, m69 bracket).
__global__ __launch_bounds__(256, 4) void attn_kernel(const unsigned short* __restrict__ qr,
                                                      const unsigned short* __restrict__ kr,
                                                      const unsigned short* __restrict__ vt,
                                                      const float* __restrict__ gate,
                                                      unsigned short* __restrict__ attn_out) {
  __shared__ float lds_m[4][32];
  __shared__ float lds_l[4][32];
  __shared__ float lds_O[3][64][33];
  const int tid = threadIdx.x;
  const int lane = tid & 63, wid = tid >> 6;
  const int l31 = lane & 31, hi = lane >> 5;

  const int fid = blockIdx.x;
  const int idx = fid >> 3;                 // 0..255
  const int bh = (fid & 7) * 4 + (idx & 3);
  const int qt = 63 - (idx >> 2);
  const int q0 = qt * 32;
  const int b = bh >> 4, h = bh & 15;
  const unsigned short* kptr = kr + (size_t)bh * TT * HDIM;
  const unsigned short* vptr = vt + (size_t)bh * TT * HDIM;
  const int q = q0 + l31;

  short8 qf[4];
#pragma unroll
  for (int st = 0; st < 4; ++st)
    qf[st] = *(const short8*)(qr + (size_t)bh * TT * HDIM + (size_t)q * HDIM + st * 16 + hi * 8);

  f32x16 o0, o1;
#pragma unroll
  for (int r = 0; r < 16; ++r) { o0[r] = 0.f; o1[r] = 0.f; }
  float mrun = -1e30f, lrun = 0.f;

  int kv_lo = q0 - WIN;
  if (kv_lo < 0) kv_lo = 0;
  const int kv_hi = q0 + 32;

  for (int kv = kv_lo + wid * 32; kv < kv_hi; kv += 128) {
    const unsigned short* kf = kptr + (size_t)kv * 64 + lane * 8;
    short8 k0 = *(const short8*)(kf);
    short8 k1 = *(const short8*)(kf + 512);
    short8 k2 = *(const short8*)(kf + 1024);
    short8 k3 = *(const short8*)(kf + 1536);

    f32x16 s;
#pragma unroll
    for (int r = 0; r < 16; ++r) s[r] = 0.f;
    s = __builtin_amdgcn_mfma_f32_32x32x16_bf16(k0, qf[0], s, 0, 0, 0);
    s = __builtin_amdgcn_mfma_f32_32x32x16_bf16(k1, qf[1], s, 0, 0, 0);
    s = __builtin_amdgcn_mfma_f32_32x32x16_bf16(k2, qf[2], s, 0, 0, 0);
    s = __builtin_amdgcn_mfma_f32_32x32x16_bf16(k3, qf[3], s, 0, 0, 0);

    if (kv == q0) {
#pragma unroll
      for (int r = 0; r < 16; ++r) {
        int key = kv + (r & 3) + 8 * (r >> 2) + 4 * hi;
        s[r] = (key <= q) ? s[r] : -1e30f;
      }
    } else if (q0 >= WIN && kv == kv_lo) {
#pragma unroll
      for (int r = 0; r < 16; ++r) {
        int key = kv + (r & 3) + 8 * (r >> 2) + 4 * hi;
        s[r] = (key + WIN >= q) ? s[r] : -1e30f;
      }
    }

    float t0 = max3f(s[0],  s[1],  s[2]);
    float t1 = max3f(s[3],  s[4],  s[5]);
    float t2 = max3f(s[6],  s[7],  s[8]);
    float t3 = max3f(s[9],  s[10], s[11]);
    float t4 = max3f(s[12], s[13], s[14]);
    float lm = fmaxf(max3f(t0, t1, t2), max3f(t3, t4, s[15]));
    lm = xmax32(lm);

    if (!__all(lm - mrun <= 8.f)) {
      float mnew = fmaxf(mrun, lm);
      float scf = __builtin_exp2f(mrun - mnew);
      mrun = mnew;
      lrun *= scf;
#pragma unroll
      for (int r = 0; r < 16; ++r) { o0[r] *= scf; o1[r] *= scf; }
    }

#pragma unroll
    for (int r = 0; r < 16; ++r) s[r] = __builtin_exp2f(s[r] - mrun);

    float c0 = (s[0] + s[1]) + (s[2] + s[3]);
    float c1 = (s[4] + s[5]) + (s[6] + s[7]);
    float c2 = (s[8] + s[9]) + (s[10] + s[11]);
    float c3 = (s[12] + s[13]) + (s[14] + s[15]);
    lrun += xsum32((c0 + c1) + (c2 + c3));

    unsigned w0 = cvt_pk_bf16(s[0],  s[1]),  w1 = cvt_pk_bf16(s[2],  s[3]);
    unsigned w2 = cvt_pk_bf16(s[4],  s[5]),  w3 = cvt_pk_bf16(s[6],  s[7]);
    unsigned w4 = cvt_pk_bf16(s[8],  s[9]),  w5 = cvt_pk_bf16(s[10], s[11]);
    unsigned w6 = cvt_pk_bf16(s[12], s[13]), w7 = cvt_pk_bf16(s[14], s[15]);
    auto s1p = __builtin_amdgcn_permlane32_swap(w0, w2, false, false);
    auto s2p = __builtin_amdgcn_permlane32_swap(w1, w3, false, false);
    auto s3p = __builtin_amdgcn_permlane32_swap(w4, w6, false, false);
    auto s4p = __builtin_amdgcn_permlane32_swap(w5, w7, false, false);
    union { unsigned u[4]; short8 s8; } pf0, pf1;
    pf0.u[0] = s1p[0]; pf0.u[1] = s2p[0]; pf0.u[2] = s1p[1]; pf0.u[3] = s2p[1];
    pf1.u[0] = s3p[0]; pf1.u[1] = s4p[0]; pf1.u[2] = s3p[1]; pf1.u[3] = s4p[1];

    const unsigned short* vf = vptr + (size_t)kv * 64 + lane * 8;
    short8 vf00 = *(const short8*)(vf);
    short8 vf01 = *(const short8*)(vf + 512);
    short8 vf10 = *(const short8*)(vf + 1024);
    short8 vf11 = *(const short8*)(vf + 1536);

    o0 = __builtin_amdgcn_mfma_f32_32x32x16_bf16(vf00, pf0.s8, o0, 0, 0, 0);
    o1 = __builtin_amdgcn_mfma_f32_32x32x16_bf16(vf10, pf0.s8, o1, 0, 0, 0);
    o0 = __builtin_amdgcn_mfma_f32_32x32x16_bf16(vf01, pf1.s8, o0, 0, 0, 0);
    o1 = __builtin_amdgcn_mfma_f32_32x32x16_bf16(vf11, pf1.s8, o1, 0, 0, 0);
  }

  // ---- combine across the 4 waves ----
  if (hi == 0) { lds_m[wid][l31] = mrun; lds_l[wid][l31] = lrun; }
  __syncthreads();
  float m0 = lds_m[0][l31], m1 = lds_m[1][l31], m2 = lds_m[2][l31], m3 = lds_m[3][l31];
  float mstar = fmaxf(fmaxf(m0, m1), fmaxf(m2, m3));
  float myscale = __builtin_exp2f(mrun - mstar);
  if (wid != 0) {
#pragma unroll
    for (int r = 0; r < 16; ++r) {
      lds_O[wid - 1][lane][r]      = o0[r] * myscale;
      lds_O[wid - 1][lane][16 + r] = o1[r] * myscale;
    }
  }
  __syncthreads();
  if (wid == 0) {
    float lstar = __builtin_exp2f(m0 - mstar) * lds_l[0][l31]
                + __builtin_exp2f(m1 - mstar) * lds_l[1][l31]
                + __builtin_exp2f(m2 - mstar) * lds_l[2][l31]
                + __builtin_exp2f(m3 - mstar) * lds_l[3][l31];
    float gv = gate[((size_t)b * TT + q) * NHEADS + h];
    float inv = gv / lstar;
    float of0[16], of1[16];
#pragma unroll
    for (int r = 0; r < 16; ++r) {
      of0[r] = o0[r] * myscale + lds_O[0][lane][r]      + lds_O[1][lane][r]      + lds_O[2][lane][r];
      of1[r] = o1[r] * myscale + lds_O[0][lane][16 + r] + lds_O[1][lane][16 + r] + lds_O[2][lane][16 + r];
    }
    unsigned short* orow = attn_out + ((size_t)b * TT + q) * DIMM + h * HDIM;
#pragma unroll
    for (int a2 = 0; a2 < 4; ++a2) {
      int d0 = a2 * 8 + hi * 4;
      union { unsigned short s[4]; uint2 u; } x0, x1;
#pragma unroll
      for (int c = 0; c < 4; ++c) {
        x0.s[c] = f2b(of0[a2 * 4 + c] * inv);
        x1.s[c] = f2b(of1[a2 * 4 + c] * inv);
      }
      *(uint2*)(orow + d0) = x0.u;
      *(uint2*)(orow + 32 + d0) = x1.u;
    }
  }
}

// ---------------- workspace layout (bytes) ----------------
#define OFF_XB    ((size_t)0)
#define OFF_WQKV  ((size_t)8388608)
#define OFF_WO    ((size_t)14680064)
#define OFF_BCAT  ((size_t)16777216)
#define OFF_QR    ((size_t)41959424)
#define OFF_KR    ((size_t)50348032)
#define OFF_VT    ((size_t)58736640)
#define OFF_ATTN  ((size_t)67125248)
#define OFF_GATE  ((size_t)75513856)

extern "C" void kernel_launch(void* const* d_in, const int* in_sizes, int n_in,
                              void* d_out, int out_size, void* d_ws, size_t ws_size,
                              hipStream_t stream) {
  const float* x    = (const float*)d_in[0];
  const float* Wq   = (const float*)d_in[1];
  const float* bq   = (const float*)d_in[2];
  const float* Wk   = (const float*)d_in[3];
  const float* bk   = (const float*)d_in[4];
  const float* Wv   = (const float*)d_in[5];
  const float* bv   = (const float*)d_in[6];
  const float* Wo   = (const float*)d_in[7];
  const float* bo   = (const float*)d_in[8];
  const float* Wg   = (const float*)d_in[9];
  const float* bg   = (const float*)d_in[10];
  const float* cosb = (const float*)d_in[11];
  const float* sinb = (const float*)d_in[12];
  float* out = (float*)d_out;
  char* ws = (char*)d_ws;

  unsigned short* xb    = (unsigned short*)(ws + OFF_XB);
  unsigned short* wqkv  = (unsigned short*)(ws + OFF_WQKV);
  unsigned short* wob   = (unsigned short*)(ws + OFF_WO);
  float*          bcat  = (float*)(ws + OFF_BCAT);
  unsigned short* q_r   = (unsigned short*)(ws + OFF_QR);
  unsigned short* k_r   = (unsigned short*)(ws + OFF_KR);
  unsigned short* v_t   = (unsigned short*)(ws + OFF_VT);
  unsigned short* attn  = (unsigned short*)(ws + OFF_ATTN);
  float*          gateb = (float*)(ws + OFF_GATE);

  prep_kernel<<<8195, 256, 0, stream>>>(x, Wq, Wk, Wv, Wo, bq, bk, bv, xb, wqkv, wob, bcat);
  gate_kernel<<<256, 256, 0, stream>>>(x, Wg, bg, gateb);

  // fused QKV projection + RoPE + relayout (no qkv intermediate)
  gemm_qkv<<<dim3(24, 32), 256, 0, stream>>>(xb, wqkv, bcat, cosb, sinb, q_r, k_r, v_t);

  // windowed causal flash attention + gate (KVBLK=32, 4 waves/SIMD)
  attn_kernel<<<2048, 256, 0, stream>>>(q_r, k_r, v_t, gateb, attn);

  // output projection: [4096,1024] @ [1024,1024]^T + bo (dbuf 2-phase)
  gemm_bt<2><<<dim3(8, 64), 256, 0, stream>>>(attn, wob, bo, out, MTOT, 1024, 1024);
}